// Round 10
// baseline (461.094 us; speedup 1.0000x reference)
//
#include <hip/hip_runtime.h>

typedef unsigned short u16;
typedef unsigned int   u32;
typedef __attribute__((ext_vector_type(8))) __bf16 bf16x8;
typedef __attribute__((ext_vector_type(4))) float   f32x4;

#define MROWS 16400     // 16 * 1025
#define NPADROWS 16512  // padded rows in bf16 buffers
#define KD 1024
#define MATEL ((size_t)NPADROWS * KD)   // elems per padded matrix
#define BUFU16 32768    // one LDS buffer: A[256][64] + B[256][64] (u16)

__device__ __forceinline__ u16 f2b(float f) {
  union { float f; u32 u; } x; x.f = f;
  return (u16)((x.u + 0x7FFFu + ((x.u >> 16) & 1u)) >> 16);
}
__device__ __forceinline__ float b2f(u16 h) {
  union { u32 u; float f; } x; x.u = ((u32)h) << 16;
  return x.f;
}

__device__ __forceinline__ void gll16(const u16* g, u16* l) {
  __builtin_amdgcn_global_load_lds(
      (const __attribute__((address_space(1))) void*)g,
      (__attribute__((address_space(3))) void*)l, 16, 0, 0);
}

// ---------------------------------------------------------------------------
// Transpose + convert weights: W[k][n] f32 -> T[n][k] bf16  (z selects matrix)
// ---------------------------------------------------------------------------
__global__ __launch_bounds__(256) void k_wtrans(
    const float* __restrict__ W0, const float* __restrict__ W1,
    const float* __restrict__ W2, const float* __restrict__ W3,
    u16* __restrict__ T)
{
  __shared__ float tile[32][33];
  int z = blockIdx.z;
  const float* W = (z == 0) ? W0 : (z == 1) ? W1 : (z == 2) ? W2 : W3;
  u16* Tz = T + (size_t)z * KD * KD;
  int tx = threadIdx.x, ty = threadIdx.y;
  int k0 = blockIdx.x * 32, n0 = blockIdx.y * 32;
#pragma unroll
  for (int r = ty; r < 32; r += 8)
    tile[r][tx] = W[(size_t)(k0 + r) * KD + n0 + tx];
  __syncthreads();
#pragma unroll
  for (int r = ty; r < 32; r += 8)
    Tz[(size_t)(n0 + r) * KD + k0 + tx] = f2b(tile[tx][r]);
}

// ---------------------------------------------------------------------------
// Convert q,k,v fp32 -> padded bf16 (zero tail rows). 8 elems/thread.
// ---------------------------------------------------------------------------
__global__ __launch_bounds__(256) void k_convert(
    const float* __restrict__ q, const float* __restrict__ k,
    const float* __restrict__ v, u16* __restrict__ dst)
{
  const size_t CH_PER_MAT = MATEL / 8;
  const size_t total = 3 * CH_PER_MAT;
  for (size_t c = (size_t)blockIdx.x * 256 + threadIdx.x; c < total;
       c += (size_t)gridDim.x * 256) {
    size_t z = c / CH_PER_MAT;
    size_t r = c - z * CH_PER_MAT;
    size_t row = r >> 7;
    int col8 = (int)(r & 127) * 8;
    u16* o = dst + z * MATEL + row * KD + col8;
    if (row < MROWS) {
      const float* s = ((z == 0) ? q : (z == 1) ? k : v) + row * KD + col8;
      float4 f0 = *(const float4*)s;
      float4 f1 = *(const float4*)(s + 4);
      ushort4 o0; o0.x = f2b(f0.x); o0.y = f2b(f0.y); o0.z = f2b(f0.z); o0.w = f2b(f0.w);
      ushort4 o1; o1.x = f2b(f1.x); o1.y = f2b(f1.y); o1.z = f2b(f1.z); o1.w = f2b(f1.w);
      *(ushort4*)o = o0; *(ushort4*)(o + 4) = o1;
    } else {
      ushort4 zz; zz.x = zz.y = zz.z = zz.w = 0;
      *(ushort4*)o = zz; *(ushort4*)(o + 4) = zz;
    }
  }
}

// ---------------------------------------------------------------------------
// 4-phase-per-K-tile bf16 MFMA GEMM (m201-style interleave on verified parts):
// BM=BN=256, BK=64, 512 thr / 8 waves (2M x 4N, wave tile 128x64),
// 2 LDS bufs x 64KB. Per K-tile: all 8 gll16 of tile kt+1 issued at phase 1
// (2-buf WAR-safe: buf^1's reads ended at the prior tile boundary), then 4
// quadrant phases {reads -> BAR -> setprio 16xMFMA -> BAR}; one vmcnt(0) at
// phase 4 (R5-proven drain semantics; loads got ~3 phases of cover).
// 8-chunk XOR swizzle = R8-verified conflict-free pattern (rule-21: linear
// gll16 dest, XOR'd global source chunk, same XOR on ds_read).
// __launch_bounds__(512,1): no spill (R9-verified; (512,2) spills -> races).
// ---------------------------------------------------------------------------
template<bool OUT_FP32>
__global__ __launch_bounds__(512, 1) void k_gemm(
    const u16* __restrict__ Ab, const u16* __restrict__ Bt,
    u16* __restrict__ Cb, float* __restrict__ Cf,
    const float* __restrict__ bias, int nwg)
{
  __shared__ u16 lds[2 * BUFU16];   // 128 KB

  // bijective XCD swizzle (m204), bn-fastest for A-panel L2 reuse
  int lin = blockIdx.x;
  int qq = nwg >> 3, r8 = nwg & 7;
  int xcd = lin & 7, pos = lin >> 3;
  int wg = (xcd < r8 ? xcd * (qq + 1) : r8 * (qq + 1) + (xcd - r8) * qq) + pos;
  int bn = wg & 3;
  int rest = wg >> 2;
  int bm = rest % 65;
  int z  = rest / 65;

  int t = threadIdx.x;
  int w = t >> 6, l = t & 63;
  int lrow = l & 15, kgrp = l >> 4;
  int wrow = w >> 2, wcol = w & 3;     // 2M x 4N wave grid

  // ---- staging: A and B each = 4 issues of 512x16B. Issue i covers rows
  // i*64 + (t>>3), phys chunk t&7; source col chunk XOR'd by row&7 (rule-21).
  int ccl = ((t & 7) ^ ((t >> 3) & 7)) * 8;
  const u16* gA[4]; const u16* gB[4];
#pragma unroll
  for (int i = 0; i < 4; ++i) {
    int prow = i * 64 + (t >> 3);
    int arow = bm * 256 + prow; if (arow > NPADROWS - 1) arow = NPADROWS - 1;
    gA[i] = Ab + (size_t)z * MATEL + (size_t)arow * KD + ccl;
    gB[i] = Bt + (size_t)z * (1024 * 1024) + (size_t)(bn * 256 + prow) * KD + ccl;
  }

  // ---- fragment read XOR terms: logical chunk c stored at c ^ (row&7);
  // row&7 == lrow&7 for all fragment rows (offsets are multiples of 8 rows).
  int xk0 = ((kgrp)     ^ (lrow & 7)) * 8;   // ks = 0
  int xk1 = ((4 + kgrp) ^ (lrow & 7)) * 8;   // ks = 1

  f32x4 acc[8][4] = {};
  bf16x8 afr[4][2], bfr2[2][2];

#define STAGE(B) { u16* L = lds + (B) * BUFU16;                         \
    _Pragma("unroll")                                                   \
    for (int i = 0; i < 4; ++i) { gll16(gA[i], L + i * 4096 + w * 512); gA[i] += 64; } \
    _Pragma("unroll")                                                   \
    for (int i = 0; i < 4; ++i) { gll16(gB[i], L + 16384 + i * 4096 + w * 512); gB[i] += 64; } }

#define BAR do { __builtin_amdgcn_sched_barrier(0);                     \
    __builtin_amdgcn_s_barrier();                                       \
    __builtin_amdgcn_sched_barrier(0); } while (0)
#define WAITV0 do { __builtin_amdgcn_sched_barrier(0);                  \
    asm volatile("s_waitcnt vmcnt(0)" ::: "memory");                    \
    __builtin_amdgcn_sched_barrier(0); } while (0)

#define READ_A(FM0) {                                                   \
    _Pragma("unroll")                                                   \
    for (int qa = 0; qa < 4; ++qa) {                                    \
      int rb = (wrow * 128 + (FM0 + qa) * 16 + lrow) * 64;              \
      afr[qa][0] = *(const bf16x8*)(Lb + rb + xk0);                     \
      afr[qa][1] = *(const bf16x8*)(Lb + rb + xk1);                     \
    } }
#define READ_B(FN0) {                                                   \
    _Pragma("unroll")                                                   \
    for (int qb = 0; qb < 2; ++qb) {                                    \
      int rb = 16384 + (wcol * 64 + (FN0 + qb) * 16 + lrow) * 64;       \
      bfr2[qb][0] = *(const bf16x8*)(Lb + rb + xk0);                    \
      bfr2[qb][1] = *(const bf16x8*)(Lb + rb + xk1);                    \
    } }
#define MFMA_Q(FM0, FN0) {                                              \
    __builtin_amdgcn_s_setprio(1);                                      \
    _Pragma("unroll")                                                   \
    for (int qa = 0; qa < 4; ++qa)                                      \
      _Pragma("unroll")                                                 \
      for (int qb = 0; qb < 2; ++qb) {                                  \
        acc[FM0 + qa][FN0 + qb] = __builtin_amdgcn_mfma_f32_16x16x32_bf16( \
            afr[qa][0], bfr2[qb][0], acc[FM0 + qa][FN0 + qb], 0, 0, 0); \
        acc[FM0 + qa][FN0 + qb] = __builtin_amdgcn_mfma_f32_16x16x32_bf16( \
            afr[qa][1], bfr2[qb][1], acc[FM0 + qa][FN0 + qb], 0, 0, 0); \
      }                                                                 \
    __builtin_amdgcn_s_setprio(0); }

  // prologue: stage tile 0, drain, sync
  STAGE(0);
  WAITV0;
  BAR;

  int buf = 0;
  for (int kt = 0; kt < 16; ++kt) {
    const u16* Lb = lds + buf * BUFU16;
    // ---- phase 1: stage kt+1 (8 issues) + quadrant (fm0-3, fn0-1)
    if (kt + 1 < 16) STAGE(buf ^ 1);
    READ_A(0);
    READ_B(0);
    BAR;
    MFMA_Q(0, 0);
    BAR;
    // ---- phase 2: quadrant (fm0-3, fn2-3), A-half0 reused from regs
    READ_B(2);
    BAR;
    MFMA_Q(0, 2);
    BAR;
    // ---- phase 3: quadrant (fm4-7, fn2-3), B-half1 reused
    READ_A(4);
    BAR;
    MFMA_Q(4, 2);
    BAR;
    // ---- phase 4: quadrant (fm4-7, fn0-1), then wait tile kt+1 resident
    READ_B(0);
    BAR;
    MFMA_Q(4, 0);
    if (kt + 1 < 16) WAITV0;
    BAR;
    buf ^= 1;
  }
#undef STAGE
#undef BAR
#undef WAITV0
#undef READ_A
#undef READ_B
#undef MFMA_Q

  // epilogue: C/D layout col=lane&15, row=(lane>>4)*4+reg  [m89-verified]
#pragma unroll
  for (int fm = 0; fm < 8; ++fm) {
#pragma unroll
    for (int fn = 0; fn < 4; ++fn) {
      int gcol = bn * 256 + wcol * 64 + fn * 16 + lrow;
#pragma unroll
      for (int r = 0; r < 4; ++r) {
        int grow = bm * 256 + wrow * 128 + fm * 16 + kgrp * 4 + r;
        if constexpr (OUT_FP32) {
          if (grow < MROWS)
            Cf[(size_t)grow * KD + gcol] = acc[fm][fn][r] + bias[gcol];
        } else {
          if (grow < NPADROWS)
            Cb[(size_t)z * MATEL + (size_t)grow * KD + gcol] = f2b(acc[fm][fn][r]);
        }
      }
    }
  }
}

// ---------------------------------------------------------------------------
// 2x2 query-tiled nearby attention (queries i>=1). One 256-thread block per
// (b, 2x2 patch tile): 4 queries x 16 heads share a 6x6+BOS = 37-key window.
// ---------------------------------------------------------------------------
__global__ __launch_bounds__(256) void k_attn_nb22(
    const u16* __restrict__ Qp, const u16* __restrict__ Kp,
    const u16* __restrict__ Vp, u16* __restrict__ AO)
{
  __shared__ float qrow[4][1024];
  __shared__ float dots[4][16][37];
  __shared__ float probs[4][16][37];
  __shared__ int   keys[37];
  __shared__ unsigned long long incm[4];

  int t = threadIdx.x;
  int b = blockIdx.x >> 8;
  int tile = blockIdx.x & 255;
  int pi0 = (tile >> 4) * 2, pj0 = (tile & 15) * 2;
  size_t rowbase = (size_t)b * 1025;

  int iq[4];
#pragma unroll
  for (int qi = 0; qi < 4; ++qi)
    iq[qi] = 1 + (pi0 + (qi >> 1)) * 32 + (pj0 + (qi & 1));

  { // stage 4 q rows as fp32
    int qi = t >> 6, off = (t & 63) * 16;
    const u16* qp = Qp + (rowbase + iq[qi]) * 1024 + off;
    uint4 a0 = *(const uint4*)qp;
    uint4 a1 = *(const uint4*)(qp + 8);
    u32 uu[8] = {a0.x, a0.y, a0.z, a0.w, a1.x, a1.y, a1.z, a1.w};
#pragma unroll
    for (int u = 0; u < 8; ++u) {
      qrow[qi][off + u * 2]     = __uint_as_float(uu[u] << 16);
      qrow[qi][off + u * 2 + 1] = __uint_as_float(uu[u] & 0xffff0000u);
    }
  }
  if (t < 37) {
    if (t < 36) {
      int r = pi0 - 2 + t / 6, c = pj0 - 2 + t % 6;
      keys[t] = (r >= 0 && r < 32 && c >= 0 && c < 32) ? (1 + r * 32 + c) : -1;
    } else {
      keys[36] = 0;  // BOS always unmasked
    }
  }
  if (t < 4) {
    int di = t >> 1, dj = t & 1;
    unsigned long long m = 1ull << 36;
    for (int j = 0; j < 36; ++j) {
      int wr = j / 6, wc = j % 6;
      if (wr >= di && wr < di + 5 && wc >= dj && wc < dj + 5) m |= 1ull << j;
    }
    incm[t] = m;
  }
  __syncthreads();

  // dots: 592 items (h,j) x 4 queries; 4 lanes cooperate per item
  int e = t & 3;
  int hD = (t >> 2) & 15;
  float qreg[4][16];
#pragma unroll
  for (int qi = 0; qi < 4; ++qi)
#pragma unroll
    for (int u = 0; u < 16; ++u)
      qreg[qi][u] = qrow[qi][hD * 64 + e * 16 + u];

#pragma unroll
  for (int p = 0; p < 10; ++p) {
    int idx = p * 64 + (t >> 2);
    float s0 = 0.f, s1 = 0.f, s2 = 0.f, s3 = 0.f;
    int key = -1;
    if (idx < 592) {
      int j = idx >> 4;
      key = keys[j];
      if (key >= 0) {
        const u16* kp = Kp + (rowbase + key) * 1024 + hD * 64 + e * 16;
        uint4 kv0 = *(const uint4*)kp;
        uint4 kv1 = *(const uint4*)(kp + 8);
        u32 uu[8] = {kv0.x, kv0.y, kv0.z, kv0.w, kv1.x, kv1.y, kv1.z, kv1.w};
#pragma unroll
        for (int u = 0; u < 8; ++u) {
          float lo = __uint_as_float(uu[u] << 16);
          float hi = __uint_as_float(uu[u] & 0xffff0000u);
          s0 += qreg[0][u * 2] * lo + qreg[0][u * 2 + 1] * hi;
          s1 += qreg[1][u * 2] * lo + qreg[1][u * 2 + 1] * hi;
          s2 += qreg[2][u * 2] * lo + qreg[2][u * 2 + 1] * hi;
          s3 += qreg[3][u * 2] * lo + qreg[3][u * 2 + 1] * hi;
        }
      }
    }
    s0 += __shfl_xor(s0, 1); s0 += __shfl_xor(s0, 2);
    s1 += __shfl_xor(s1, 1); s1 += __shfl_xor(s1, 2);
    s2 += __shfl_xor(s2, 1); s2 += __shfl_xor(s2, 2);
    s3 += __shfl_xor(s3, 1); s3 += __shfl_xor(s3, 2);
    if (idx < 592) {
      int j = idx >> 4;
      float sv = (e == 0) ? s0 : (e == 1) ? s1 : (e == 2) ? s2 : s3;
      dots[e][hD][j] = (key >= 0) ? sv * 0.125f : -3.0e38f;
    }
  }
  __syncthreads();

  { // softmax: 64 rows (qi,h) x 4 lanes each
    int row = t >> 2;
    int qi = row >> 4, hh = row & 15;
    unsigned long long inc = incm[qi];
    float dv[10];
    float m = -3.0e38f;
#pragma unroll
    for (int s = 0; s < 10; ++s) {
      int j = e + s * 4;
      float d = -3.0e38f;
      if (j < 37) {
        d = dots[qi][hh][j];
        if (!((inc >> j) & 1)) d = -3.0e38f;
      }
      dv[s] = d;
      m = fmaxf(m, d);
    }
    m = fmaxf(m, __shfl_xor(m, 1));
    m = fmaxf(m, __shfl_xor(m, 2));
    float sum = 0.f;
    float pv[10];
#pragma unroll
    for (int s = 0; s < 10; ++s) {
      int j = e + s * 4;
      float p = (j < 37) ? __expf(dv[s] - m) : 0.f;
      pv[s] = p; sum += p;
    }
    sum += __shfl_xor(sum, 1);
    sum += __shfl_xor(sum, 2);
    float inv = 1.f / sum;
#pragma unroll
    for (int s = 0; s < 10; ++s) {
      int j = e + s * 4;
      if (j < 37) probs[qi][hh][j] = pv[s] * inv;
    }
  }
  __syncthreads();

  { // PV: thread t owns dims c0=t*4 (head h=t>>4), accumulates 4 queries
    int h = t >> 4;
    int c0 = t * 4;
    float a[4][4] = {};
    for (int j = 0; j < 37; ++j) {
      int key = keys[j];
      if (key < 0) continue;
      ushort4 vv = *(const ushort4*)(Vp + (rowbase + key) * 1024 + c0);
      float v0 = b2f(vv.x), v1 = b2f(vv.y), v2 = b2f(vv.z), v3 = b2f(vv.w);
#pragma unroll
      for (int qi = 0; qi < 4; ++qi) {
        float p = probs[qi][h][j];
        a[qi][0] += p * v0; a[qi][1] += p * v1;
        a[qi][2] += p * v2; a[qi][3] += p * v3;
      }
    }
#pragma unroll
    for (int qi = 0; qi < 4; ++qi) {
      ushort4 o;
      o.x = f2b(a[qi][0]); o.y = f2b(a[qi][1]);
      o.z = f2b(a[qi][2]); o.w = f2b(a[qi][3]);
      *(ushort4*)&AO[(rowbase + iq[qi]) * 1024 + c0] = o;
    }
  }
}

// ---------------------------------------------------------------------------
// Dense attention for BOS query (i=0): attends to all 1025 keys.
// ---------------------------------------------------------------------------
__global__ __launch_bounds__(256) void k_attn_row0(
    const u16* __restrict__ Qp, const u16* __restrict__ Kp,
    const u16* __restrict__ Vp, u16* __restrict__ AO)
{
  __shared__ float q0[64];
  __shared__ float pr[1025];
  __shared__ float red[256];
  int t = threadIdx.x;
  int b = blockIdx.x >> 4, h = blockIdx.x & 15;
  size_t rowbase = (size_t)b * 1025;

  if (t < 64) q0[t] = b2f(Qp[rowbase * 1024 + h * 64 + t]);
  __syncthreads();

  float lmax = -3.0e38f;
  for (int j = t; j < 1025; j += 256) {
    const u16* kp = Kp + (rowbase + j) * 1024 + h * 64;
    float s = 0.f;
#pragma unroll
    for (int e = 0; e < 64; e += 4) {
      ushort4 kv = *(const ushort4*)(kp + e);
      s += q0[e + 0] * b2f(kv.x) + q0[e + 1] * b2f(kv.y)
         + q0[e + 2] * b2f(kv.z) + q0[e + 3] * b2f(kv.w);
    }
    s *= 0.125f;
    pr[j] = s;
    lmax = fmaxf(lmax, s);
  }
  red[t] = lmax; __syncthreads();
  for (int s = 128; s > 0; s >>= 1) {
    if (t < s) red[t] = fmaxf(red[t], red[t + s]);
    __syncthreads();
  }
  float m = red[0]; __syncthreads();

  float lsum = 0.f;
  for (int j = t; j < 1025; j += 256) {
    float p = __expf(pr[j] - m);
    pr[j] = p; lsum += p;
  }
  red[t] = lsum; __syncthreads();
  for (int s = 128; s > 0; s >>= 1) {
    if (t < s) red[t] += red[t + s];
    __syncthreads();
  }
  float inv = 1.f / red[0]; __syncthreads();

  int d = t & 63, grp = t >> 6;
  float a = 0.f;
  for (int j = grp; j < 1025; j += 4)
    a += pr[j] * b2f(Vp[(rowbase + j) * 1024 + h * 64 + d]);
  red[t] = a; __syncthreads();
  if (t < 64) {
    float tot = (red[t] + red[t + 64]) + (red[t + 128] + red[t + 192]);
    AO[rowbase * 1024 + h * 64 + t] = f2b(tot * inv);
  }
}

// ---------------------------------------------------------------------------
extern "C" void kernel_launch(void* const* d_in, const int* in_sizes, int n_in,
                              void* d_out, int out_size, void* d_ws, size_t ws_size,
                              hipStream_t stream) {
  const float* q  = (const float*)d_in[0];
  const float* k  = (const float*)d_in[1];
  const float* v  = (const float*)d_in[2];
  const float* Wq = (const float*)d_in[3];
  const float* Wk = (const float*)d_in[4];
  const float* Wv = (const float*)d_in[5];
  const float* Wo = (const float*)d_in[6];
  const float* bo = (const float*)d_in[7];
  float* out = (float*)d_out;

  // workspace (u16 units), ~211.3 MB total:
  //   wt:  4M            (Wq^T,Wk^T,Wv^T,Wo^T bf16)
  //   qb:  3*MATEL       (q,k,v converted padded bf16)  [AO aliases qb]
  //   Qp:  3*MATEL       (projected Q,K,V bf16 padded)
  u16* wt = (u16*)d_ws;
  u16* qb = wt + (size_t)4 * 1024 * 1024;
  u16* Qp = qb + 3 * MATEL;
  u16* Kp = Qp + MATEL;
  u16* Vp = Kp + MATEL;
  u16* AO = qb;  // alias: qb dead after projection GEMM

  k_wtrans<<<dim3(32, 32, 4), dim3(32, 8), 0, stream>>>(Wq, Wk, Wv, Wo, wt);
  k_convert<<<2048, 256, 0, stream>>>(q, k, v, qb);

  // Q/K/V projections: 65 M-tiles x 4 N-tiles x 3 z = 780 blocks
  k_gemm<false><<<780, 512, 0, stream>>>(qb, wt, Qp, nullptr, nullptr, 780);

  // 2x2 query-tiled nearby attention: 16 b x 256 tiles = 4096 blocks
  k_attn_nb22<<<4096, 256, 0, stream>>>(Qp, Kp, Vp, AO);
  k_attn_row0<<<256, 256, 0, stream>>>(Qp, Kp, Vp, AO);

  // output projection: 65 x 4 = 260 blocks, fp32 out + bias
  k_gemm<true><<<260, 512, 0, stream>>>(AO, wt + (size_t)3 * 1024 * 1024,
                                        nullptr, out, bo, 260);
}

// Round 11
// 446.850 us; speedup vs baseline: 1.0319x; 1.0319x over previous
//
#include <hip/hip_runtime.h>

typedef unsigned short u16;
typedef unsigned int   u32;
typedef __attribute__((ext_vector_type(8))) __bf16 bf16x8;
typedef __attribute__((ext_vector_type(4))) float   f32x4;

#define MROWS 16400     // 16 * 1025
#define NPADROWS 16512  // padded rows in bf16 buffers
#define KD 1024
#define MATEL ((size_t)NPADROWS * KD)   // elems per padded matrix

__device__ __forceinline__ u16 f2b(float f) {
  union { float f; u32 u; } x; x.f = f;
  return (u16)((x.u + 0x7FFFu + ((x.u >> 16) & 1u)) >> 16);
}
__device__ __forceinline__ float b2f(u16 h) {
  union { u32 u; float f; } x; x.u = ((u32)h) << 16;
  return x.f;
}

__device__ __forceinline__ void gll16(const void* g, u16* l) {
  __builtin_amdgcn_global_load_lds(
      (const __attribute__((address_space(1))) void*)g,
      (__attribute__((address_space(3))) void*)l, 16, 0, 0);
}

// ---------------------------------------------------------------------------
// Transpose + convert weights: W[k][n] f32 -> T[n][k] bf16  (z selects matrix)
// ---------------------------------------------------------------------------
__global__ __launch_bounds__(256) void k_wtrans(
    const float* __restrict__ W0, const float* __restrict__ W1,
    const float* __restrict__ W2, const float* __restrict__ W3,
    u16* __restrict__ T)
{
  __shared__ float tile[32][33];
  int z = blockIdx.z;
  const float* W = (z == 0) ? W0 : (z == 1) ? W1 : (z == 2) ? W2 : W3;
  u16* Tz = T + (size_t)z * KD * KD;
  int tx = threadIdx.x, ty = threadIdx.y;
  int k0 = blockIdx.x * 32, n0 = blockIdx.y * 32;
#pragma unroll
  for (int r = ty; r < 32; r += 8)
    tile[r][tx] = W[(size_t)(k0 + r) * KD + n0 + tx];
  __syncthreads();
#pragma unroll
  for (int r = ty; r < 32; r += 8)
    Tz[(size_t)(n0 + r) * KD + k0 + tx] = f2b(tile[tx][r]);
}

// ---------------------------------------------------------------------------
// Fused convert+QKV GEMM: A fp32 read DIRECTLY from q/k/v via gll16 into
// fp32 LDS (no convert pass, no ds_write); bf16 cast happens during the
// LDS->register fragment read. 128x128 tile, BK=32, 4 waves 2x2,
// double-buffered LDS 2 x 24KB (A fp32 16KB + B bf16 8KB), 3 blocks/CU.
// R5-proven sync (one __syncthreads per K-tile). Rule-21 XOR swizzles:
// A 8-chunk (16B) by row&7, B 4-chunk by row&3 — linear gll16 dest,
// pre-swizzled global source, same XOR on reads (R8-verified conflict-free).
// ---------------------------------------------------------------------------
__global__ __launch_bounds__(256) void k_gemm_qkv(
    const float* __restrict__ Aq, const float* __restrict__ Ak,
    const float* __restrict__ Av, const u16* __restrict__ Bt,
    u16* __restrict__ Cb, int nwg)
{
  __shared__ u16 lds[2 * 12288];

  int lin = blockIdx.x;
  int cpx = nwg >> 3;                       // nwg % 8 == 0
  int swz = (lin & 7) * cpx + (lin >> 3);   // bijective XCD swizzle
  int bn = swz & 7;
  int rest = swz >> 3;
  int bm = rest % 129;
  int z  = rest / 129;
  const float* Af = (z == 0) ? Aq : (z == 1) ? Ak : Av;

  int t = threadIdx.x;
  int w = t >> 6, l = t & 63;
  int lrow = l & 15, kgrp = l >> 4;
  int wm = (w >> 1) * 64, wn = (w & 1) * 64;

  // ---- A staging (fp32): 4 issues of 256x16B. Thread: row i*32+(t>>3),
  // phys 16B-chunk t&7; source col = (chunk ^ (row&7)) (pre-swizzled).
  int acol = ((t & 7) ^ ((t >> 3) & 7)) * 4;   // float units
  const float* gA[4];
#pragma unroll
  for (int i = 0; i < 4; ++i) {
    int row = bm * 128 + i * 32 + (t >> 3);
    if (row > MROWS - 1) row = MROWS - 1;
    gA[i] = Af + (size_t)row * KD + acol;
  }
  // ---- B staging (bf16): 2 issues (R5 map) + 4-chunk swizzle
  int srow = w * 16 + (l >> 2);
  int scolB = ((l & 3) ^ ((l >> 2) & 3)) * 8;  // u16 units
  const u16* gB  = Bt + (size_t)z * (1024 * 1024) + (size_t)(bn * 128 + srow) * KD + scolB;
  const u16* gB2 = gB + (size_t)64 * KD;
  int dB0 = 8192 + w * 512;
  int dB1 = 8192 + 2048 + w * 512;

  f32x4 acc[4][4] = {};

#define STAGEQ(B) { u16* L = lds + (B) * 12288;                         \
    _Pragma("unroll")                                                   \
    for (int i = 0; i < 4; ++i) { gll16(gA[i], L + i * 2048 + w * 512); gA[i] += 32; } \
    gll16(gB, L + dB0); gll16(gB2, L + dB1); gB += 32; gB2 += 32; }

  STAGEQ(0);
  __syncthreads();

  int buf = 0;
#pragma unroll 2
  for (int kt = 0; kt < 32; ++kt) {
    if (kt + 1 < 32) STAGEQ(buf ^ 1);   // issue next tile FIRST

    const u16* Lb = lds + buf * 12288;
    const float* LA = (const float*)Lb;
    bf16x8 af[4], bfr[4];
    int x7 = lrow & 7;
#pragma unroll
    for (int fm = 0; fm < 4; ++fm) {
      int rb = (wm + fm * 16 + lrow) * 32;   // float units, 32 floats/row
      f32x4 lo = *(const f32x4*)(LA + rb + (((2 * kgrp)     ^ x7) * 4));
      f32x4 hi = *(const f32x4*)(LA + rb + (((2 * kgrp + 1) ^ x7) * 4));
      bf16x8 v;
      v[0] = (__bf16)lo[0]; v[1] = (__bf16)lo[1];
      v[2] = (__bf16)lo[2]; v[3] = (__bf16)lo[3];
      v[4] = (__bf16)hi[0]; v[5] = (__bf16)hi[1];
      v[6] = (__bf16)hi[2]; v[7] = (__bf16)hi[3];
      af[fm] = v;
    }
#pragma unroll
    for (int fn = 0; fn < 4; ++fn)
      bfr[fn] = *(const bf16x8*)(Lb + 8192 + (wn + fn * 16 + lrow) * 32
                                 + ((kgrp ^ (lrow & 3)) * 8));
#pragma unroll
    for (int fm = 0; fm < 4; ++fm)
#pragma unroll
      for (int fn = 0; fn < 4; ++fn)
        acc[fm][fn] = __builtin_amdgcn_mfma_f32_16x16x32_bf16(af[fm], bfr[fn], acc[fm][fn], 0, 0, 0);

    __syncthreads();
    buf ^= 1;
  }
#undef STAGEQ

  // epilogue: C/D layout col=lane&15, row=(lane>>4)*4+reg  [m89-verified]
#pragma unroll
  for (int fm = 0; fm < 4; ++fm) {
#pragma unroll
    for (int fn = 0; fn < 4; ++fn) {
      int gcol = bn * 128 + wn + fn * 16 + lrow;
#pragma unroll
      for (int r = 0; r < 4; ++r) {
        int grow = bm * 128 + wm + fm * 16 + kgrp * 4 + r;
        Cb[(size_t)z * MATEL + (size_t)grow * KD + gcol] = f2b(acc[fm][fn][r]);
      }
    }
  }
}

// ---------------------------------------------------------------------------
// Out-proj GEMM (R8 verbatim, verified): BK=64 + 8-chunk XOR swizzle,
// 128x128 tile, 4 waves 2x2, double-buffered 64KB LDS, 1 syncthreads/K-tile.
// ---------------------------------------------------------------------------
template<bool OUT_FP32>
__global__ __launch_bounds__(256) void k_gemm(
    const u16* __restrict__ Ab, const u16* __restrict__ Bt,
    u16* __restrict__ Cb, float* __restrict__ Cf,
    const float* __restrict__ bias, int nwg)
{
  __shared__ u16 lds[2 * 16384];

  int lin = blockIdx.x;
  int cpx = nwg >> 3;
  int swz = (lin & 7) * cpx + (lin >> 3);
  int bn = swz & 7;
  int rest = swz >> 3;
  int bm = rest % 129;
  int z  = rest / 129;

  int t = threadIdx.x;
  int w = t >> 6, l = t & 63;
  int lrow = l & 15, kgrp = l >> 4;
  int wm = (w >> 1) * 64, wn = (w & 1) * 64;

  int ccl = ((t & 7) ^ ((t >> 3) & 7)) * 8;
  const u16* gA[4]; const u16* gB[4];
#pragma unroll
  for (int i = 0; i < 4; ++i) {
    int prow = i * 32 + (t >> 3);
    gA[i] = Ab + (size_t)z * MATEL + (size_t)(bm * 128 + prow) * KD + ccl;
    gB[i] = Bt + (size_t)z * (1024 * 1024) + (size_t)(bn * 128 + prow) * KD + ccl;
  }

  int aoff[4], boff[4];
#pragma unroll
  for (int fm = 0; fm < 4; ++fm)
    aoff[fm] = (wm + fm * 16 + lrow) * 64 + ((kgrp ^ (l & 7)) * 8);
#pragma unroll
  for (int fn = 0; fn < 4; ++fn)
    boff[fn] = 8192 + (wn + fn * 16 + lrow) * 64 + ((kgrp ^ (l & 7)) * 8);

  f32x4 acc[4][4] = {};

#define STAGE(B) { u16* L = lds + (B) * 16384;                          \
    _Pragma("unroll")                                                   \
    for (int i = 0; i < 4; ++i) { gll16(gA[i], L + i * 2048 + w * 512); gA[i] += 64; } \
    _Pragma("unroll")                                                   \
    for (int i = 0; i < 4; ++i) { gll16(gB[i], L + 8192 + i * 2048 + w * 512); gB[i] += 64; } }

  STAGE(0);
  __syncthreads();

  int buf = 0;
#pragma unroll 2
  for (int kt = 0; kt < 16; ++kt) {
    if (kt + 1 < 16) STAGE(buf ^ 1);

    const u16* Lb = lds + buf * 16384;
#pragma unroll
    for (int ks = 0; ks < 2; ++ks) {
      bf16x8 af[4], bfr[4];
#pragma unroll
      for (int fm = 0; fm < 4; ++fm)
        af[fm] = *(const bf16x8*)(Lb + (aoff[fm] ^ (ks << 5)));
#pragma unroll
      for (int fn = 0; fn < 4; ++fn)
        bfr[fn] = *(const bf16x8*)(Lb + (boff[fn] ^ (ks << 5)));
#pragma unroll
      for (int fm = 0; fm < 4; ++fm)
#pragma unroll
        for (int fn = 0; fn < 4; ++fn)
          acc[fm][fn] = __builtin_amdgcn_mfma_f32_16x16x32_bf16(af[fm], bfr[fn], acc[fm][fn], 0, 0, 0);
    }

    __syncthreads();
    buf ^= 1;
  }
#undef STAGE

#pragma unroll
  for (int fm = 0; fm < 4; ++fm) {
#pragma unroll
    for (int fn = 0; fn < 4; ++fn) {
      int gcol = bn * 128 + wn + fn * 16 + lrow;
#pragma unroll
      for (int r = 0; r < 4; ++r) {
        int grow = bm * 128 + wm + fm * 16 + kgrp * 4 + r;
        if constexpr (OUT_FP32) {
          if (grow < MROWS)
            Cf[(size_t)grow * KD + gcol] = acc[fm][fn][r] + bias[gcol];
        } else {
          Cb[(size_t)z * MATEL + (size_t)grow * KD + gcol] = f2b(acc[fm][fn][r]);
        }
      }
    }
  }
}

// ---------------------------------------------------------------------------
// Merged attention: blocks [0,4096) = 2x2 query-tiled nearby attention;
// blocks [4096,4352) = dense BOS-row attention. One launch, one gap saved.
// ---------------------------------------------------------------------------
__global__ __launch_bounds__(256) void k_attn(
    const u16* __restrict__ Qp, const u16* __restrict__ Kp,
    const u16* __restrict__ Vp, u16* __restrict__ AO)
{
  int t = threadIdx.x;

  if (blockIdx.x < 4096) {
    // ---------------- nearby attention (R6-verified body) ----------------
    __shared__ float qrow[4][1024];
    __shared__ float dots[4][16][37];
    __shared__ float probs[4][16][37];
    __shared__ int   keys[37];
    __shared__ unsigned long long incm[4];

    int b = blockIdx.x >> 8;
    int tile = blockIdx.x & 255;
    int pi0 = (tile >> 4) * 2, pj0 = (tile & 15) * 2;
    size_t rowbase = (size_t)b * 1025;

    int iq[4];
#pragma unroll
    for (int qi = 0; qi < 4; ++qi)
      iq[qi] = 1 + (pi0 + (qi >> 1)) * 32 + (pj0 + (qi & 1));

    { // stage 4 q rows as fp32
      int qi = t >> 6, off = (t & 63) * 16;
      const u16* qp = Qp + (rowbase + iq[qi]) * 1024 + off;
      uint4 a0 = *(const uint4*)qp;
      uint4 a1 = *(const uint4*)(qp + 8);
      u32 uu[8] = {a0.x, a0.y, a0.z, a0.w, a1.x, a1.y, a1.z, a1.w};
#pragma unroll
      for (int u = 0; u < 8; ++u) {
        qrow[qi][off + u * 2]     = __uint_as_float(uu[u] << 16);
        qrow[qi][off + u * 2 + 1] = __uint_as_float(uu[u] & 0xffff0000u);
      }
    }
    if (t < 37) {
      if (t < 36) {
        int r = pi0 - 2 + t / 6, c = pj0 - 2 + t % 6;
        keys[t] = (r >= 0 && r < 32 && c >= 0 && c < 32) ? (1 + r * 32 + c) : -1;
      } else {
        keys[36] = 0;
      }
    }
    if (t < 4) {
      int di = t >> 1, dj = t & 1;
      unsigned long long m = 1ull << 36;
      for (int j = 0; j < 36; ++j) {
        int wr = j / 6, wc = j % 6;
        if (wr >= di && wr < di + 5 && wc >= dj && wc < dj + 5) m |= 1ull << j;
      }
      incm[t] = m;
    }
    __syncthreads();

    int e = t & 3;
    int hD = (t >> 2) & 15;
    float qreg[4][16];
#pragma unroll
    for (int qi = 0; qi < 4; ++qi)
#pragma unroll
      for (int u = 0; u < 16; ++u)
        qreg[qi][u] = qrow[qi][hD * 64 + e * 16 + u];

#pragma unroll
    for (int p = 0; p < 10; ++p) {
      int idx = p * 64 + (t >> 2);
      float s0 = 0.f, s1 = 0.f, s2 = 0.f, s3 = 0.f;
      int key = -1;
      if (idx < 592) {
        int j = idx >> 4;
        key = keys[j];
        if (key >= 0) {
          const u16* kp = Kp + (rowbase + key) * 1024 + hD * 64 + e * 16;
          uint4 kv0 = *(const uint4*)kp;
          uint4 kv1 = *(const uint4*)(kp + 8);
          u32 uu[8] = {kv0.x, kv0.y, kv0.z, kv0.w, kv1.x, kv1.y, kv1.z, kv1.w};
#pragma unroll
          for (int u = 0; u < 8; ++u) {
            float lo = __uint_as_float(uu[u] << 16);
            float hi = __uint_as_float(uu[u] & 0xffff0000u);
            s0 += qreg[0][u * 2] * lo + qreg[0][u * 2 + 1] * hi;
            s1 += qreg[1][u * 2] * lo + qreg[1][u * 2 + 1] * hi;
            s2 += qreg[2][u * 2] * lo + qreg[2][u * 2 + 1] * hi;
            s3 += qreg[3][u * 2] * lo + qreg[3][u * 2 + 1] * hi;
          }
        }
      }
      s0 += __shfl_xor(s0, 1); s0 += __shfl_xor(s0, 2);
      s1 += __shfl_xor(s1, 1); s1 += __shfl_xor(s1, 2);
      s2 += __shfl_xor(s2, 1); s2 += __shfl_xor(s2, 2);
      s3 += __shfl_xor(s3, 1); s3 += __shfl_xor(s3, 2);
      if (idx < 592) {
        int j = idx >> 4;
        float sv = (e == 0) ? s0 : (e == 1) ? s1 : (e == 2) ? s2 : s3;
        dots[e][hD][j] = (key >= 0) ? sv * 0.125f : -3.0e38f;
      }
    }
    __syncthreads();

    { // softmax
      int row = t >> 2;
      int qi = row >> 4, hh = row & 15;
      unsigned long long inc = incm[qi];
      float dv[10];
      float m = -3.0e38f;
#pragma unroll
      for (int s = 0; s < 10; ++s) {
        int j = e + s * 4;
        float d = -3.0e38f;
        if (j < 37) {
          d = dots[qi][hh][j];
          if (!((inc >> j) & 1)) d = -3.0e38f;
        }
        dv[s] = d;
        m = fmaxf(m, d);
      }
      m = fmaxf(m, __shfl_xor(m, 1));
      m = fmaxf(m, __shfl_xor(m, 2));
      float sum = 0.f;
      float pv[10];
#pragma unroll
      for (int s = 0; s < 10; ++s) {
        int j = e + s * 4;
        float p = (j < 37) ? __expf(dv[s] - m) : 0.f;
        pv[s] = p; sum += p;
      }
      sum += __shfl_xor(sum, 1);
      sum += __shfl_xor(sum, 2);
      float inv = 1.f / sum;
#pragma unroll
      for (int s = 0; s < 10; ++s) {
        int j = e + s * 4;
        if (j < 37) probs[qi][hh][j] = pv[s] * inv;
      }
    }
    __syncthreads();

    { // PV
      int h = t >> 4;
      int c0 = t * 4;
      float a[4][4] = {};
      for (int j = 0; j < 37; ++j) {
        int key = keys[j];
        if (key < 0) continue;
        ushort4 vv = *(const ushort4*)(Vp + (rowbase + key) * 1024 + c0);
        float v0 = b2f(vv.x), v1 = b2f(vv.y), v2 = b2f(vv.z), v3 = b2f(vv.w);
#pragma unroll
        for (int qi = 0; qi < 4; ++qi) {
          float p = probs[qi][h][j];
          a[qi][0] += p * v0; a[qi][1] += p * v1;
          a[qi][2] += p * v2; a[qi][3] += p * v3;
        }
      }
#pragma unroll
      for (int qi = 0; qi < 4; ++qi) {
        ushort4 o;
        o.x = f2b(a[qi][0]); o.y = f2b(a[qi][1]);
        o.z = f2b(a[qi][2]); o.w = f2b(a[qi][3]);
        *(ushort4*)&AO[(rowbase + iq[qi]) * 1024 + c0] = o;
      }
    }
  } else {
    // ---------------- BOS-row dense attention (verified body) ----------------
    __shared__ float q0[64];
    __shared__ float pr[1025];
    __shared__ float red[256];
    int bid = blockIdx.x - 4096;
    int b = bid >> 4, h = bid & 15;
    size_t rowbase = (size_t)b * 1025;

    if (t < 64) q0[t] = b2f(Qp[rowbase * 1024 + h * 64 + t]);
    __syncthreads();

    float lmax = -3.0e38f;
    for (int j = t; j < 1025; j += 256) {
      const u16* kp = Kp + (rowbase + j) * 1024 + h * 64;
      float s = 0.f;
#pragma unroll
      for (int e = 0; e < 64; e += 4) {
        ushort4 kv = *(const ushort4*)(kp + e);
        s += q0[e + 0] * b2f(kv.x) + q0[e + 1] * b2f(kv.y)
           + q0[e + 2] * b2f(kv.z) + q0[e + 3] * b2f(kv.w);
      }
      s *= 0.125f;
      pr[j] = s;
      lmax = fmaxf(lmax, s);
    }
    red[t] = lmax; __syncthreads();
    for (int s = 128; s > 0; s >>= 1) {
      if (t < s) red[t] = fmaxf(red[t], red[t + s]);
      __syncthreads();
    }
    float m = red[0]; __syncthreads();

    float lsum = 0.f;
    for (int j = t; j < 1025; j += 256) {
      float p = __expf(pr[j] - m);
      pr[j] = p; lsum += p;
    }
    red[t] = lsum; __syncthreads();
    for (int s = 128; s > 0; s >>= 1) {
      if (t < s) red[t] += red[t + s];
      __syncthreads();
    }
    float inv = 1.f / red[0]; __syncthreads();

    int d = t & 63, grp = t >> 6;
    float a = 0.f;
    for (int j = grp; j < 1025; j += 4)
      a += pr[j] * b2f(Vp[(rowbase + j) * 1024 + h * 64 + d]);
    red[t] = a; __syncthreads();
    if (t < 64) {
      float tot = (red[t] + red[t + 64]) + (red[t + 128] + red[t + 192]);
      AO[rowbase * 1024 + h * 64 + t] = f2b(tot * inv);
    }
  }
}

// ---------------------------------------------------------------------------
extern "C" void kernel_launch(void* const* d_in, const int* in_sizes, int n_in,
                              void* d_out, int out_size, void* d_ws, size_t ws_size,
                              hipStream_t stream) {
  const float* q  = (const float*)d_in[0];
  const float* k  = (const float*)d_in[1];
  const float* v  = (const float*)d_in[2];
  const float* Wq = (const float*)d_in[3];
  const float* Wk = (const float*)d_in[4];
  const float* Wv = (const float*)d_in[5];
  const float* Wo = (const float*)d_in[6];
  const float* bo = (const float*)d_in[7];
  float* out = (float*)d_out;

  // workspace (u16 units), ~143.7 MB:
  //   wt:  4M            (Wq^T,Wk^T,Wv^T,Wo^T bf16)
  //   AO:  MATEL         (attention output bf16 padded; tail rows unused)
  //   Qp/Kp/Vp: 3*MATEL  (projected Q,K,V bf16 padded)
  u16* wt = (u16*)d_ws;
  u16* AO = wt + (size_t)4 * 1024 * 1024;
  u16* Qp = AO + MATEL;
  u16* Kp = Qp + MATEL;
  u16* Vp = Kp + MATEL;

  k_wtrans<<<dim3(32, 32, 4), dim3(32, 8), 0, stream>>>(Wq, Wk, Wv, Wo, wt);

  // fused convert+QKV projection (A fp32 direct): nwg = 8*129*3 = 3096
  k_gemm_qkv<<<3096, 256, 0, stream>>>(q, k, v, wt, Qp, 3096);

  // merged attention: 4096 nearby blocks + 256 BOS-row blocks
  k_attn<<<4352, 256, 0, stream>>>(Qp, Kp, Vp, AO);

  // output projection (A bf16 = AO): nwg = 8*129 = 1032
  k_gemm<true><<<1032, 256, 0, stream>>>(AO, wt + (size_t)3 * 1024 * 1024,
                                         nullptr, out, bo, 1032);
}

// Round 12
// 436.159 us; speedup vs baseline: 1.0572x; 1.0245x over previous
//
#include <hip/hip_runtime.h>

typedef unsigned short u16;
typedef unsigned int   u32;
typedef __attribute__((ext_vector_type(8))) __bf16 bf16x8;
typedef __attribute__((ext_vector_type(4))) float   f32x4;

#define MROWS 16400     // 16 * 1025
#define NPADROWS 16512  // padded rows in bf16 buffers
#define KD 1024
#define MATEL ((size_t)NPADROWS * KD)   // elems per padded matrix
#define NT 32           // K-tiles of 32

__device__ __forceinline__ u16 f2b(float f) {
  union { float f; u32 u; } x; x.f = f;
  return (u16)((x.u + 0x7FFFu + ((x.u >> 16) & 1u)) >> 16);
}
__device__ __forceinline__ float b2f(u16 h) {
  union { u32 u; float f; } x; x.u = ((u32)h) << 16;
  return x.f;
}

__device__ __forceinline__ void gll16(const u16* g, u16* l) {
  __builtin_amdgcn_global_load_lds(
      (const __attribute__((address_space(1))) void*)g,
      (__attribute__((address_space(3))) void*)l, 16, 0, 0);
}

// ---------------------------------------------------------------------------
// Merged prologue: blocks [0,4096) transpose+convert weights (W[k][n] f32 ->
// T[n][k] bf16, z = bid>>10); blocks [4096,6144) convert q/k/v fp32 -> padded
// bf16 (grid-stride over 2048 virtual blocks).
// ---------------------------------------------------------------------------
__global__ __launch_bounds__(256) void k_pre(
    const float* __restrict__ W0, const float* __restrict__ W1,
    const float* __restrict__ W2, const float* __restrict__ W3,
    u16* __restrict__ T,
    const float* __restrict__ q, const float* __restrict__ k,
    const float* __restrict__ v, u16* __restrict__ dst)
{
  if (blockIdx.x < 4096) {
    __shared__ float tile[32][33];
    int z = blockIdx.x >> 10;
    int tl = blockIdx.x & 1023;
    int k0 = (tl >> 5) * 32, n0 = (tl & 31) * 32;
    int tx = threadIdx.x & 31, ty = threadIdx.x >> 5;
    const float* W = (z == 0) ? W0 : (z == 1) ? W1 : (z == 2) ? W2 : W3;
    u16* Tz = T + (size_t)z * KD * KD;
#pragma unroll
    for (int r = ty; r < 32; r += 8)
      tile[r][tx] = W[(size_t)(k0 + r) * KD + n0 + tx];
    __syncthreads();
#pragma unroll
    for (int r = ty; r < 32; r += 8)
      Tz[(size_t)(n0 + r) * KD + k0 + tx] = f2b(tile[tx][r]);
  } else {
    int cid = blockIdx.x - 4096;
    const size_t CH_PER_MAT = MATEL / 8;
    const size_t total = 3 * CH_PER_MAT;
    for (size_t c = (size_t)cid * 256 + threadIdx.x; c < total;
         c += (size_t)2048 * 256) {
      size_t z = c / CH_PER_MAT;
      size_t r = c - z * CH_PER_MAT;
      size_t row = r >> 7;
      int col8 = (int)(r & 127) * 8;
      u16* o = dst + z * MATEL + row * KD + col8;
      if (row < MROWS) {
        const float* s = ((z == 0) ? q : (z == 1) ? k : v) + row * KD + col8;
        float4 f0 = *(const float4*)s;
        float4 f1 = *(const float4*)(s + 4);
        ushort4 o0; o0.x = f2b(f0.x); o0.y = f2b(f0.y); o0.z = f2b(f0.z); o0.w = f2b(f0.w);
        ushort4 o1; o1.x = f2b(f1.x); o1.y = f2b(f1.y); o1.z = f2b(f1.z); o1.w = f2b(f1.w);
        *(ushort4*)o = o0; *(ushort4*)(o + 4) = o1;
      } else {
        ushort4 zz; zz.x = zz.y = zz.z = zz.w = 0;
        *(ushort4*)o = zz; *(ushort4*)(o + 4) = zz;
      }
    }
  }
}

// ---------------------------------------------------------------------------
// 2-phase prefetch bf16 MFMA GEMM, BK=32 + quarter-wave-correct XOR swizzle.
// 128x128 tile, 4 waves 2x2, double-buffered LDS 32KB -> 5 blocks/CU.
// Swizzle (rule-21: linear gll16 dest, pre-swizzled source, same XOR on read):
//   LDS row r, phys 16B-chunk p holds logical chunk p ^ ((r>>1)&3).
//   Read of logical chunk kgrp at row r -> slot 4*(r&1) + (kgrp^((r>>1)&3)):
//   within each quarter-wave (16 lanes, kgrp const) this spans all 8 slots
//   exactly twice -> conflict-free under the quarter-wave bank model that
//   explains R5/R7/R8/R11 counters. Sync = R5-proven 1 __syncthreads/K-tile.
// ---------------------------------------------------------------------------
template<bool OUT_FP32>
__global__ __launch_bounds__(256) void k_gemm(
    const u16* __restrict__ Ab, const u16* __restrict__ Bt,
    u16* __restrict__ Cb, float* __restrict__ Cf,
    const float* __restrict__ bias, int nwg)
{
  __shared__ u16 lds[2 * 8192];   // buf: A[128][32] (4096) + B[128][32] (4096)

  int lin = blockIdx.x;
  int cpx = nwg >> 3;                       // nwg % 8 == 0
  int swz = (lin & 7) * cpx + (lin >> 3);   // bijective XCD swizzle
  int bn = swz & 7;
  int rest = swz >> 3;
  int bm = rest % 129;
  int z  = rest / 129;

  int t = threadIdx.x;
  int w = t >> 6, l = t & 63;
  int lrow = l & 15, kgrp = l >> 4;
  int wm = (w >> 1) * 64, wn = (w & 1) * 64;

  // staging (R5 geometry + source swizzle): wave w rows w*16..+15 per issue;
  // phys chunk = l&3, source logical chunk = (l&3) ^ ((srow>>1)&3).
  int srow = w * 16 + (l >> 2);
  int scol = ((l & 3) ^ ((srow >> 1) & 3)) * 8;
  const u16* gA  = Ab + (size_t)z * MATEL + (size_t)(bm * 128 + srow) * KD + scol;
  const u16* gA2 = gA + (size_t)64 * KD;   // row+64: (r>>1)&3 unchanged
  const u16* gB  = Bt + (size_t)z * (1024 * 1024) + (size_t)(bn * 128 + srow) * KD + scol;
  const u16* gB2 = gB + (size_t)64 * KD;
  int dA0 = w * 512;
  int dA1 = 2048 + w * 512;
  int dB0 = 4096 + w * 512;
  int dB1 = 6144 + w * 512;

  // fragment read offsets: logical chunk kgrp at row -> phys kgrp^((lrow>>1)&3)
  int qr = (lrow >> 1) & 3;   // fragment rows offset by multiples of 16 -> qr const
  int aoff[4], boff[4];
#pragma unroll
  for (int fm = 0; fm < 4; ++fm)
    aoff[fm] = (wm + fm * 16 + lrow) * 32 + ((kgrp ^ qr) * 8);
#pragma unroll
  for (int fn = 0; fn < 4; ++fn)
    boff[fn] = 4096 + (wn + fn * 16 + lrow) * 32 + ((kgrp ^ qr) * 8);

  f32x4 acc[4][4] = {};

#define STAGE(B) { u16* L = lds + (B) * 8192;                         \
    gll16(gA,  L + dA0); gll16(gA2, L + dA1);                         \
    gll16(gB,  L + dB0); gll16(gB2, L + dB1);                         \
    gA += 32; gA2 += 32; gB += 32; gB2 += 32; }

  STAGE(0);
  __syncthreads();

  int buf = 0;
#pragma unroll 2
  for (int kt = 0; kt < NT; ++kt) {
    if (kt + 1 < NT) STAGE(buf ^ 1);   // issue next tile FIRST

    const u16* Lb = lds + buf * 8192;
    bf16x8 af[4], bfr[4];
#pragma unroll
    for (int fm = 0; fm < 4; ++fm)
      af[fm] = *(const bf16x8*)(Lb + aoff[fm]);
#pragma unroll
    for (int fn = 0; fn < 4; ++fn)
      bfr[fn] = *(const bf16x8*)(Lb + boff[fn]);
#pragma unroll
    for (int fm = 0; fm < 4; ++fm)
#pragma unroll
      for (int fn = 0; fn < 4; ++fn)
        acc[fm][fn] = __builtin_amdgcn_mfma_f32_16x16x32_bf16(af[fm], bfr[fn], acc[fm][fn], 0, 0, 0);

    __syncthreads();
    buf ^= 1;
  }
#undef STAGE

  // epilogue: C/D layout col=lane&15, row=(lane>>4)*4+reg  [m89-verified]
#pragma unroll
  for (int fm = 0; fm < 4; ++fm) {
#pragma unroll
    for (int fn = 0; fn < 4; ++fn) {
      int gcol = bn * 128 + wn + fn * 16 + lrow;
#pragma unroll
      for (int r = 0; r < 4; ++r) {
        int grow = bm * 128 + wm + fm * 16 + kgrp * 4 + r;
        if constexpr (OUT_FP32) {
          if (grow < MROWS)
            Cf[(size_t)grow * KD + gcol] = acc[fm][fn][r] + bias[gcol];
        } else {
          Cb[(size_t)z * MATEL + (size_t)grow * KD + gcol] = f2b(acc[fm][fn][r]);
        }
      }
    }
  }
}

// ---------------------------------------------------------------------------
// Merged attention (R11-verified): blocks [0,4096) = 2x2 query-tiled nearby
// attention; blocks [4096,4352) = dense BOS-row attention.
// ---------------------------------------------------------------------------
__global__ __launch_bounds__(256) void k_attn(
    const u16* __restrict__ Qp, const u16* __restrict__ Kp,
    const u16* __restrict__ Vp, u16* __restrict__ AO)
{
  int t = threadIdx.x;

  if (blockIdx.x < 4096) {
    __shared__ float qrow[4][1024];
    __shared__ float dots[4][16][37];
    __shared__ float probs[4][16][37];
    __shared__ int   keys[37];
    __shared__ unsigned long long incm[4];

    int b = blockIdx.x >> 8;
    int tile = blockIdx.x & 255;
    int pi0 = (tile >> 4) * 2, pj0 = (tile & 15) * 2;
    size_t rowbase = (size_t)b * 1025;

    int iq[4];
#pragma unroll
    for (int qi = 0; qi < 4; ++qi)
      iq[qi] = 1 + (pi0 + (qi >> 1)) * 32 + (pj0 + (qi & 1));

    { // stage 4 q rows as fp32
      int qi = t >> 6, off = (t & 63) * 16;
      const u16* qp = Qp + (rowbase + iq[qi]) * 1024 + off;
      uint4 a0 = *(const uint4*)qp;
      uint4 a1 = *(const uint4*)(qp + 8);
      u32 uu[8] = {a0.x, a0.y, a0.z, a0.w, a1.x, a1.y, a1.z, a1.w};
#pragma unroll
      for (int u = 0; u < 8; ++u) {
        qrow[qi][off + u * 2]     = __uint_as_float(uu[u] << 16);
        qrow[qi][off + u * 2 + 1] = __uint_as_float(uu[u] & 0xffff0000u);
      }
    }
    if (t < 37) {
      if (t < 36) {
        int r = pi0 - 2 + t / 6, c = pj0 - 2 + t % 6;
        keys[t] = (r >= 0 && r < 32 && c >= 0 && c < 32) ? (1 + r * 32 + c) : -1;
      } else {
        keys[36] = 0;
      }
    }
    if (t < 4) {
      int di = t >> 1, dj = t & 1;
      unsigned long long m = 1ull << 36;
      for (int j = 0; j < 36; ++j) {
        int wr = j / 6, wc = j % 6;
        if (wr >= di && wr < di + 5 && wc >= dj && wc < dj + 5) m |= 1ull << j;
      }
      incm[t] = m;
    }
    __syncthreads();

    int e = t & 3;
    int hD = (t >> 2) & 15;
    float qreg[4][16];
#pragma unroll
    for (int qi = 0; qi < 4; ++qi)
#pragma unroll
      for (int u = 0; u < 16; ++u)
        qreg[qi][u] = qrow[qi][hD * 64 + e * 16 + u];

#pragma unroll
    for (int p = 0; p < 10; ++p) {
      int idx = p * 64 + (t >> 2);
      float s0 = 0.f, s1 = 0.f, s2 = 0.f, s3 = 0.f;
      int key = -1;
      if (idx < 592) {
        int j = idx >> 4;
        key = keys[j];
        if (key >= 0) {
          const u16* kp = Kp + (rowbase + key) * 1024 + hD * 64 + e * 16;
          uint4 kv0 = *(const uint4*)kp;
          uint4 kv1 = *(const uint4*)(kp + 8);
          u32 uu[8] = {kv0.x, kv0.y, kv0.z, kv0.w, kv1.x, kv1.y, kv1.z, kv1.w};
#pragma unroll
          for (int u = 0; u < 8; ++u) {
            float lo = __uint_as_float(uu[u] << 16);
            float hi = __uint_as_float(uu[u] & 0xffff0000u);
            s0 += qreg[0][u * 2] * lo + qreg[0][u * 2 + 1] * hi;
            s1 += qreg[1][u * 2] * lo + qreg[1][u * 2 + 1] * hi;
            s2 += qreg[2][u * 2] * lo + qreg[2][u * 2 + 1] * hi;
            s3 += qreg[3][u * 2] * lo + qreg[3][u * 2 + 1] * hi;
          }
        }
      }
      s0 += __shfl_xor(s0, 1); s0 += __shfl_xor(s0, 2);
      s1 += __shfl_xor(s1, 1); s1 += __shfl_xor(s1, 2);
      s2 += __shfl_xor(s2, 1); s2 += __shfl_xor(s2, 2);
      s3 += __shfl_xor(s3, 1); s3 += __shfl_xor(s3, 2);
      if (idx < 592) {
        int j = idx >> 4;
        float sv = (e == 0) ? s0 : (e == 1) ? s1 : (e == 2) ? s2 : s3;
        dots[e][hD][j] = (key >= 0) ? sv * 0.125f : -3.0e38f;
      }
    }
    __syncthreads();

    { // softmax
      int row = t >> 2;
      int qi = row >> 4, hh = row & 15;
      unsigned long long inc = incm[qi];
      float dv[10];
      float m = -3.0e38f;
#pragma unroll
      for (int s = 0; s < 10; ++s) {
        int j = e + s * 4;
        float d = -3.0e38f;
        if (j < 37) {
          d = dots[qi][hh][j];
          if (!((inc >> j) & 1)) d = -3.0e38f;
        }
        dv[s] = d;
        m = fmaxf(m, d);
      }
      m = fmaxf(m, __shfl_xor(m, 1));
      m = fmaxf(m, __shfl_xor(m, 2));
      float sum = 0.f;
      float pv[10];
#pragma unroll
      for (int s = 0; s < 10; ++s) {
        int j = e + s * 4;
        float p = (j < 37) ? __expf(dv[s] - m) : 0.f;
        pv[s] = p; sum += p;
      }
      sum += __shfl_xor(sum, 1);
      sum += __shfl_xor(sum, 2);
      float inv = 1.f / sum;
#pragma unroll
      for (int s = 0; s < 10; ++s) {
        int j = e + s * 4;
        if (j < 37) probs[qi][hh][j] = pv[s] * inv;
      }
    }
    __syncthreads();

    { // PV
      int h = t >> 4;
      int c0 = t * 4;
      float a[4][4] = {};
      for (int j = 0; j < 37; ++j) {
        int key = keys[j];
        if (key < 0) continue;
        ushort4 vv = *(const ushort4*)(Vp + (rowbase + key) * 1024 + c0);
        float v0 = b2f(vv.x), v1 = b2f(vv.y), v2 = b2f(vv.z), v3 = b2f(vv.w);
#pragma unroll
        for (int qi = 0; qi < 4; ++qi) {
          float p = probs[qi][h][j];
          a[qi][0] += p * v0; a[qi][1] += p * v1;
          a[qi][2] += p * v2; a[qi][3] += p * v3;
        }
      }
#pragma unroll
      for (int qi = 0; qi < 4; ++qi) {
        ushort4 o;
        o.x = f2b(a[qi][0]); o.y = f2b(a[qi][1]);
        o.z = f2b(a[qi][2]); o.w = f2b(a[qi][3]);
        *(ushort4*)&AO[(rowbase + iq[qi]) * 1024 + c0] = o;
      }
    }
  } else {
    __shared__ float q0[64];
    __shared__ float pr[1025];
    __shared__ float red[256];
    int bid = blockIdx.x - 4096;
    int b = bid >> 4, h = bid & 15;
    size_t rowbase = (size_t)b * 1025;

    if (t < 64) q0[t] = b2f(Qp[rowbase * 1024 + h * 64 + t]);
    __syncthreads();

    float lmax = -3.0e38f;
    for (int j = t; j < 1025; j += 256) {
      const u16* kp = Kp + (rowbase + j) * 1024 + h * 64;
      float s = 0.f;
#pragma unroll
      for (int e = 0; e < 64; e += 4) {
        ushort4 kv = *(const ushort4*)(kp + e);
        s += q0[e + 0] * b2f(kv.x) + q0[e + 1] * b2f(kv.y)
           + q0[e + 2] * b2f(kv.z) + q0[e + 3] * b2f(kv.w);
      }
      s *= 0.125f;
      pr[j] = s;
      lmax = fmaxf(lmax, s);
    }
    red[t] = lmax; __syncthreads();
    for (int s = 128; s > 0; s >>= 1) {
      if (t < s) red[t] = fmaxf(red[t], red[t + s]);
      __syncthreads();
    }
    float m = red[0]; __syncthreads();

    float lsum = 0.f;
    for (int j = t; j < 1025; j += 256) {
      float p = __expf(pr[j] - m);
      pr[j] = p; lsum += p;
    }
    red[t] = lsum; __syncthreads();
    for (int s = 128; s > 0; s >>= 1) {
      if (t < s) red[t] += red[t + s];
      __syncthreads();
    }
    float inv = 1.f / red[0]; __syncthreads();

    int d = t & 63, grp = t >> 6;
    float a = 0.f;
    for (int j = grp; j < 1025; j += 4)
      a += pr[j] * b2f(Vp[(rowbase + j) * 1024 + h * 64 + d]);
    red[t] = a; __syncthreads();
    if (t < 64) {
      float tot = (red[t] + red[t + 64]) + (red[t + 128] + red[t + 192]);
      AO[rowbase * 1024 + h * 64 + t] = f2b(tot * inv);
    }
  }
}

// ---------------------------------------------------------------------------
extern "C" void kernel_launch(void* const* d_in, const int* in_sizes, int n_in,
                              void* d_out, int out_size, void* d_ws, size_t ws_size,
                              hipStream_t stream) {
  const float* q  = (const float*)d_in[0];
  const float* k  = (const float*)d_in[1];
  const float* v  = (const float*)d_in[2];
  const float* Wq = (const float*)d_in[3];
  const float* Wk = (const float*)d_in[4];
  const float* Wv = (const float*)d_in[5];
  const float* Wo = (const float*)d_in[6];
  const float* bo = (const float*)d_in[7];
  float* out = (float*)d_out;

  // workspace (u16 units), ~211.3 MB total:
  //   wt:  4M            (Wq^T,Wk^T,Wv^T,Wo^T bf16)
  //   qb:  3*MATEL       (q,k,v converted padded bf16)  [AO aliases qb]
  //   Qp:  3*MATEL       (projected Q,K,V bf16 padded)
  u16* wt = (u16*)d_ws;
  u16* qb = wt + (size_t)4 * 1024 * 1024;
  u16* Qp = qb + 3 * MATEL;
  u16* Kp = Qp + MATEL;
  u16* Vp = Kp + MATEL;
  u16* AO = qb;  // alias: qb dead after projection GEMM

  // merged wtrans (4096 blocks) + convert (2048 virtual blocks)
  k_pre<<<6144, 256, 0, stream>>>(Wq, Wk, Wv, Wo, wt, q, k, v, qb);

  // Q/K/V projections (z = 0,1,2 via grid decode): nwg = 8*129*3 = 3096
  k_gemm<false><<<3096, 256, 0, stream>>>(qb, wt, Qp, nullptr, nullptr, 3096);

  // merged attention: 4096 nearby blocks + 256 BOS-row blocks
  k_attn<<<4352, 256, 0, stream>>>(Qp, Kp, Vp, AO);

  // output projection: nwg = 8*129 = 1032, fp32 out + bias
  k_gemm<true><<<1032, 256, 0, stream>>>(AO, wt + (size_t)3 * 1024 * 1024,
                                         nullptr, out, bo, 1032);
}

// Round 13
// 431.209 us; speedup vs baseline: 1.0693x; 1.0115x over previous
//
#include <hip/hip_runtime.h>

typedef unsigned short u16;
typedef unsigned int   u32;
typedef __attribute__((ext_vector_type(8))) __bf16 bf16x8;
typedef __attribute__((ext_vector_type(4))) float   f32x4;

#define MROWS 16400     // 16 * 1025
#define NPADROWS 16512  // padded rows in bf16 buffers
#define KD 1024
#define MATEL ((size_t)NPADROWS * KD)   // elems per padded matrix
#define NT 32           // K-tiles of 32

__device__ __forceinline__ u16 f2b(float f) {
  union { float f; u32 u; } x; x.f = f;
  return (u16)((x.u + 0x7FFFu + ((x.u >> 16) & 1u)) >> 16);
}
__device__ __forceinline__ float b2f(u16 h) {
  union { u32 u; float f; } x; x.u = ((u32)h) << 16;
  return x.f;
}

__device__ __forceinline__ void gll16(const u16* g, u16* l) {
  __builtin_amdgcn_global_load_lds(
      (const __attribute__((address_space(1))) void*)g,
      (__attribute__((address_space(3))) void*)l, 16, 0, 0);
}

// ---------------------------------------------------------------------------
// Merged prologue: blocks [0,4096) transpose+convert weights; blocks
// [4096,6144) convert q/k/v fp32 -> padded bf16 (grid-stride).
// ---------------------------------------------------------------------------
__global__ __launch_bounds__(256) void k_pre(
    const float* __restrict__ W0, const float* __restrict__ W1,
    const float* __restrict__ W2, const float* __restrict__ W3,
    u16* __restrict__ T,
    const float* __restrict__ q, const float* __restrict__ k,
    const float* __restrict__ v, u16* __restrict__ dst)
{
  if (blockIdx.x < 4096) {
    __shared__ float tile[32][33];
    int z = blockIdx.x >> 10;
    int tl = blockIdx.x & 1023;
    int k0 = (tl >> 5) * 32, n0 = (tl & 31) * 32;
    int tx = threadIdx.x & 31, ty = threadIdx.x >> 5;
    const float* W = (z == 0) ? W0 : (z == 1) ? W1 : (z == 2) ? W2 : W3;
    u16* Tz = T + (size_t)z * KD * KD;
#pragma unroll
    for (int r = ty; r < 32; r += 8)
      tile[r][tx] = W[(size_t)(k0 + r) * KD + n0 + tx];
    __syncthreads();
#pragma unroll
    for (int r = ty; r < 32; r += 8)
      Tz[(size_t)(n0 + r) * KD + k0 + tx] = f2b(tile[tx][r]);
  } else {
    int cid = blockIdx.x - 4096;
    const size_t CH_PER_MAT = MATEL / 8;
    const size_t total = 3 * CH_PER_MAT;
    for (size_t c = (size_t)cid * 256 + threadIdx.x; c < total;
         c += (size_t)2048 * 256) {
      size_t z = c / CH_PER_MAT;
      size_t r = c - z * CH_PER_MAT;
      size_t row = r >> 7;
      int col8 = (int)(r & 127) * 8;
      u16* o = dst + z * MATEL + row * KD + col8;
      if (row < MROWS) {
        const float* s = ((z == 0) ? q : (z == 1) ? k : v) + row * KD + col8;
        float4 f0 = *(const float4*)s;
        float4 f1 = *(const float4*)(s + 4);
        ushort4 o0; o0.x = f2b(f0.x); o0.y = f2b(f0.y); o0.z = f2b(f0.z); o0.w = f2b(f0.w);
        ushort4 o1; o1.x = f2b(f1.x); o1.y = f2b(f1.y); o1.z = f2b(f1.z); o1.w = f2b(f1.w);
        *(ushort4*)o = o0; *(ushort4*)(o + 4) = o1;
      } else {
        ushort4 zz; zz.x = zz.y = zz.z = zz.w = 0;
        *(ushort4*)o = zz; *(ushort4*)(o + 4) = zz;
      }
    }
  }
}

// ---------------------------------------------------------------------------
// 2-phase prefetch bf16 MFMA GEMM (R12-verified, FROZEN): BK=32 +
// quarter-wave-correct XOR swizzle, 128x128 tile, 4 waves 2x2, 32KB LDS.
// ---------------------------------------------------------------------------
template<bool OUT_FP32>
__global__ __launch_bounds__(256) void k_gemm(
    const u16* __restrict__ Ab, const u16* __restrict__ Bt,
    u16* __restrict__ Cb, float* __restrict__ Cf,
    const float* __restrict__ bias, int nwg)
{
  __shared__ u16 lds[2 * 8192];   // buf: A[128][32] (4096) + B[128][32] (4096)

  int lin = blockIdx.x;
  int cpx = nwg >> 3;                       // nwg % 8 == 0
  int swz = (lin & 7) * cpx + (lin >> 3);   // bijective XCD swizzle
  int bn = swz & 7;
  int rest = swz >> 3;
  int bm = rest % 129;
  int z  = rest / 129;

  int t = threadIdx.x;
  int w = t >> 6, l = t & 63;
  int lrow = l & 15, kgrp = l >> 4;
  int wm = (w >> 1) * 64, wn = (w & 1) * 64;

  int srow = w * 16 + (l >> 2);
  int scol = ((l & 3) ^ ((srow >> 1) & 3)) * 8;
  const u16* gA  = Ab + (size_t)z * MATEL + (size_t)(bm * 128 + srow) * KD + scol;
  const u16* gA2 = gA + (size_t)64 * KD;   // row+64: (r>>1)&3 unchanged
  const u16* gB  = Bt + (size_t)z * (1024 * 1024) + (size_t)(bn * 128 + srow) * KD + scol;
  const u16* gB2 = gB + (size_t)64 * KD;
  int dA0 = w * 512;
  int dA1 = 2048 + w * 512;
  int dB0 = 4096 + w * 512;
  int dB1 = 6144 + w * 512;

  int qr = (lrow >> 1) & 3;
  int aoff[4], boff[4];
#pragma unroll
  for (int fm = 0; fm < 4; ++fm)
    aoff[fm] = (wm + fm * 16 + lrow) * 32 + ((kgrp ^ qr) * 8);
#pragma unroll
  for (int fn = 0; fn < 4; ++fn)
    boff[fn] = 4096 + (wn + fn * 16 + lrow) * 32 + ((kgrp ^ qr) * 8);

  f32x4 acc[4][4] = {};

#define STAGE(B) { u16* L = lds + (B) * 8192;                         \
    gll16(gA,  L + dA0); gll16(gA2, L + dA1);                         \
    gll16(gB,  L + dB0); gll16(gB2, L + dB1);                         \
    gA += 32; gA2 += 32; gB += 32; gB2 += 32; }

  STAGE(0);
  __syncthreads();

  int buf = 0;
#pragma unroll 2
  for (int kt = 0; kt < NT; ++kt) {
    if (kt + 1 < NT) STAGE(buf ^ 1);   // issue next tile FIRST

    const u16* Lb = lds + buf * 8192;
    bf16x8 af[4], bfr[4];
#pragma unroll
    for (int fm = 0; fm < 4; ++fm)
      af[fm] = *(const bf16x8*)(Lb + aoff[fm]);
#pragma unroll
    for (int fn = 0; fn < 4; ++fn)
      bfr[fn] = *(const bf16x8*)(Lb + boff[fn]);
#pragma unroll
    for (int fm = 0; fm < 4; ++fm)
#pragma unroll
      for (int fn = 0; fn < 4; ++fn)
        acc[fm][fn] = __builtin_amdgcn_mfma_f32_16x16x32_bf16(af[fm], bfr[fn], acc[fm][fn], 0, 0, 0);

    __syncthreads();
    buf ^= 1;
  }
#undef STAGE

  // epilogue: C/D layout col=lane&15, row=(lane>>4)*4+reg  [m89-verified]
#pragma unroll
  for (int fm = 0; fm < 4; ++fm) {
#pragma unroll
    for (int fn = 0; fn < 4; ++fn) {
      int gcol = bn * 128 + wn + fn * 16 + lrow;
#pragma unroll
      for (int r = 0; r < 4; ++r) {
        int grow = bm * 128 + wm + fm * 16 + kgrp * 4 + r;
        if constexpr (OUT_FP32) {
          if (grow < MROWS)
            Cf[(size_t)grow * KD + gcol] = acc[fm][fn][r] + bias[gcol];
        } else {
          Cb[(size_t)z * MATEL + (size_t)grow * KD + gcol] = f2b(acc[fm][fn][r]);
        }
      }
    }
  }
}

// ---------------------------------------------------------------------------
// Merged attention v2 (occupancy-optimized): blocks [0,4096) = 2x2 query-
// tiled nearby attention; blocks [4096,4352) = dense BOS-row attention.
// Changes vs R12: (1) q staged DIRECTLY global->registers (per-wave the
// (hD,e) map tiles the 2KB q-row contiguously -> coalesced; kills the 16KB
// qrow LDS and its 16-way-conflicted read); (2) dots/probs share one
// in-place buffer (each slot read-then-written by the same lane).
// LDS ~9.7KB -> 8 blocks/CU (wave cap) vs 4 before.
// ---------------------------------------------------------------------------
__global__ __launch_bounds__(256) void k_attn(
    const u16* __restrict__ Qp, const u16* __restrict__ Kp,
    const u16* __restrict__ Vp, u16* __restrict__ AO)
{
  int t = threadIdx.x;

  if (blockIdx.x < 4096) {
    __shared__ float sdp[4][16][37];   // dots, then probs in place
    __shared__ int   keys[37];
    __shared__ unsigned long long incm[4];

    int b = blockIdx.x >> 8;
    int tile = blockIdx.x & 255;
    int pi0 = (tile >> 4) * 2, pj0 = (tile & 15) * 2;
    size_t rowbase = (size_t)b * 1025;

    int iq[4];
#pragma unroll
    for (int qi = 0; qi < 4; ++qi)
      iq[qi] = 1 + (pi0 + (qi >> 1)) * 32 + (pj0 + (qi & 1));

    if (t < 37) {
      if (t < 36) {
        int r = pi0 - 2 + t / 6, c = pj0 - 2 + t % 6;
        keys[t] = (r >= 0 && r < 32 && c >= 0 && c < 32) ? (1 + r * 32 + c) : -1;
      } else {
        keys[36] = 0;  // BOS always unmasked
      }
    }
    if (t < 4) {
      int di = t >> 1, dj = t & 1;
      unsigned long long m = 1ull << 36;
      for (int j = 0; j < 36; ++j) {
        int wr = j / 6, wc = j % 6;
        if (wr >= di && wr < di + 5 && wc >= dj && wc < dj + 5) m |= 1ull << j;
      }
      incm[t] = m;
    }

    // direct global->reg q staging: thread owns head hD, k-seg e (16 elems)
    int e = t & 3;
    int hD = (t >> 2) & 15;
    float qreg[4][16];
#pragma unroll
    for (int qi = 0; qi < 4; ++qi) {
      const u16* qp = Qp + (rowbase + iq[qi]) * 1024 + hD * 64 + e * 16;
      uint4 a0 = *(const uint4*)qp;
      uint4 a1 = *(const uint4*)(qp + 8);
      u32 uu[8] = {a0.x, a0.y, a0.z, a0.w, a1.x, a1.y, a1.z, a1.w};
#pragma unroll
      for (int u = 0; u < 8; ++u) {
        qreg[qi][u * 2]     = __uint_as_float(uu[u] << 16);
        qreg[qi][u * 2 + 1] = __uint_as_float(uu[u] & 0xffff0000u);
      }
    }
    __syncthreads();   // keys/incm ready

    // dots: 592 items (j,h) x 4 queries; 4 lanes cooperate per item.
    // Per p-iteration a wave covers ONE key row contiguously (2KB).
#pragma unroll
    for (int p = 0; p < 10; ++p) {
      int idx = p * 64 + (t >> 2);
      float s0 = 0.f, s1 = 0.f, s2 = 0.f, s3 = 0.f;
      int key = -1;
      if (idx < 592) {
        int j = idx >> 4;
        key = keys[j];
        if (key >= 0) {
          const u16* kp = Kp + (rowbase + key) * 1024 + hD * 64 + e * 16;
          uint4 kv0 = *(const uint4*)kp;
          uint4 kv1 = *(const uint4*)(kp + 8);
          u32 uu[8] = {kv0.x, kv0.y, kv0.z, kv0.w, kv1.x, kv1.y, kv1.z, kv1.w};
#pragma unroll
          for (int u = 0; u < 8; ++u) {
            float lo = __uint_as_float(uu[u] << 16);
            float hi = __uint_as_float(uu[u] & 0xffff0000u);
            s0 += qreg[0][u * 2] * lo + qreg[0][u * 2 + 1] * hi;
            s1 += qreg[1][u * 2] * lo + qreg[1][u * 2 + 1] * hi;
            s2 += qreg[2][u * 2] * lo + qreg[2][u * 2 + 1] * hi;
            s3 += qreg[3][u * 2] * lo + qreg[3][u * 2 + 1] * hi;
          }
        }
      }
      s0 += __shfl_xor(s0, 1); s0 += __shfl_xor(s0, 2);
      s1 += __shfl_xor(s1, 1); s1 += __shfl_xor(s1, 2);
      s2 += __shfl_xor(s2, 1); s2 += __shfl_xor(s2, 2);
      s3 += __shfl_xor(s3, 1); s3 += __shfl_xor(s3, 2);
      if (idx < 592) {
        int j = idx >> 4;
        float sv = (e == 0) ? s0 : (e == 1) ? s1 : (e == 2) ? s2 : s3;
        sdp[e][hD][j] = (key >= 0) ? sv * 0.125f : -3.0e38f;
      }
    }
    __syncthreads();

    { // softmax in place: 64 rows (qi,h) x 4 lanes; lane e scans e,e+4,...
      int row = t >> 2;
      int qi = row >> 4, hh = row & 15;
      unsigned long long inc = incm[qi];
      float dv[10];
      float m = -3.0e38f;
#pragma unroll
      for (int s = 0; s < 10; ++s) {
        int j = e + s * 4;
        float d = -3.0e38f;
        if (j < 37) {
          d = sdp[qi][hh][j];
          if (!((inc >> j) & 1)) d = -3.0e38f;
        }
        dv[s] = d;
        m = fmaxf(m, d);
      }
      m = fmaxf(m, __shfl_xor(m, 1));
      m = fmaxf(m, __shfl_xor(m, 2));
      float sum = 0.f;
      float pv[10];
#pragma unroll
      for (int s = 0; s < 10; ++s) {
        int j = e + s * 4;
        float p = (j < 37) ? __expf(dv[s] - m) : 0.f;
        pv[s] = p; sum += p;
      }
      sum += __shfl_xor(sum, 1);
      sum += __shfl_xor(sum, 2);
      float inv = 1.f / sum;
#pragma unroll
      for (int s = 0; s < 10; ++s) {
        int j = e + s * 4;
        if (j < 37) sdp[qi][hh][j] = pv[s] * inv;
      }
    }
    __syncthreads();

    { // PV: thread t owns dims c0=t*4 (head h=t>>4), accumulates 4 queries
      int h = t >> 4;
      int c0 = t * 4;
      float a[4][4] = {};
      for (int j = 0; j < 37; ++j) {
        int key = keys[j];
        if (key < 0) continue;
        ushort4 vv = *(const ushort4*)(Vp + (rowbase + key) * 1024 + c0);
        float v0 = b2f(vv.x), v1 = b2f(vv.y), v2 = b2f(vv.z), v3 = b2f(vv.w);
#pragma unroll
        for (int qi = 0; qi < 4; ++qi) {
          float p = sdp[qi][h][j];
          a[qi][0] += p * v0; a[qi][1] += p * v1;
          a[qi][2] += p * v2; a[qi][3] += p * v3;
        }
      }
#pragma unroll
      for (int qi = 0; qi < 4; ++qi) {
        ushort4 o;
        o.x = f2b(a[qi][0]); o.y = f2b(a[qi][1]);
        o.z = f2b(a[qi][2]); o.w = f2b(a[qi][3]);
        *(ushort4*)&AO[(rowbase + iq[qi]) * 1024 + c0] = o;
      }
    }
  } else {
    // ---------------- BOS-row dense attention (verified body) --------------
    __shared__ float q0[64];
    __shared__ float pr[1025];
    __shared__ float red[256];
    int bid = blockIdx.x - 4096;
    int b = bid >> 4, h = bid & 15;
    size_t rowbase = (size_t)b * 1025;

    if (t < 64) q0[t] = b2f(Qp[rowbase * 1024 + h * 64 + t]);
    __syncthreads();

    float lmax = -3.0e38f;
    for (int j = t; j < 1025; j += 256) {
      const u16* kp = Kp + (rowbase + j) * 1024 + h * 64;
      float s = 0.f;
#pragma unroll
      for (int e = 0; e < 64; e += 4) {
        ushort4 kv = *(const ushort4*)(kp + e);
        s += q0[e + 0] * b2f(kv.x) + q0[e + 1] * b2f(kv.y)
           + q0[e + 2] * b2f(kv.z) + q0[e + 3] * b2f(kv.w);
      }
      s *= 0.125f;
      pr[j] = s;
      lmax = fmaxf(lmax, s);
    }
    red[t] = lmax; __syncthreads();
    for (int s = 128; s > 0; s >>= 1) {
      if (t < s) red[t] = fmaxf(red[t], red[t + s]);
      __syncthreads();
    }
    float m = red[0]; __syncthreads();

    float lsum = 0.f;
    for (int j = t; j < 1025; j += 256) {
      float p = __expf(pr[j] - m);
      pr[j] = p; lsum += p;
    }
    red[t] = lsum; __syncthreads();
    for (int s = 128; s > 0; s >>= 1) {
      if (t < s) red[t] += red[t + s];
      __syncthreads();
    }
    float inv = 1.f / red[0]; __syncthreads();

    int d = t & 63, grp = t >> 6;
    float a = 0.f;
    for (int j = grp; j < 1025; j += 4)
      a += pr[j] * b2f(Vp[(rowbase + j) * 1024 + h * 64 + d]);
    red[t] = a; __syncthreads();
    if (t < 64) {
      float tot = (red[t] + red[t + 64]) + (red[t + 128] + red[t + 192]);
      AO[rowbase * 1024 + h * 64 + t] = f2b(tot * inv);
    }
  }
}

// ---------------------------------------------------------------------------
extern "C" void kernel_launch(void* const* d_in, const int* in_sizes, int n_in,
                              void* d_out, int out_size, void* d_ws, size_t ws_size,
                              hipStream_t stream) {
  const float* q  = (const float*)d_in[0];
  const float* k  = (const float*)d_in[1];
  const float* v  = (const float*)d_in[2];
  const float* Wq = (const float*)d_in[3];
  const float* Wk = (const float*)d_in[4];
  const float* Wv = (const float*)d_in[5];
  const float* Wo = (const float*)d_in[6];
  const float* bo = (const float*)d_in[7];
  float* out = (float*)d_out;

  // workspace (u16 units), ~211.3 MB total:
  //   wt:  4M            (Wq^T,Wk^T,Wv^T,Wo^T bf16)
  //   qb:  3*MATEL       (q,k,v converted padded bf16)  [AO aliases qb]
  //   Qp:  3*MATEL       (projected Q,K,V bf16 padded)
  u16* wt = (u16*)d_ws;
  u16* qb = wt + (size_t)4 * 1024 * 1024;
  u16* Qp = qb + 3 * MATEL;
  u16* Kp = Qp + MATEL;
  u16* Vp = Kp + MATEL;
  u16* AO = qb;  // alias: qb dead after projection GEMM

  // merged wtrans (4096 blocks) + convert (2048 virtual blocks)
  k_pre<<<6144, 256, 0, stream>>>(Wq, Wk, Wv, Wo, wt, q, k, v, qb);

  // Q/K/V projections (z = 0,1,2 via grid decode): nwg = 8*129*3 = 3096
  k_gemm<false><<<3096, 256, 0, stream>>>(qb, wt, Qp, nullptr, nullptr, 3096);

  // merged attention: 4096 nearby blocks + 256 BOS-row blocks
  k_attn<<<4352, 256, 0, stream>>>(Qp, Kp, Vp, AO);

  // output projection: nwg = 8*129 = 1032, fp32 out + bias
  k_gemm<true><<<1032, 256, 0, stream>>>(AO, wt + (size_t)3 * 1024 * 1024,
                                         nullptr, out, bo, 1032);
}

// Round 14
// 355.140 us; speedup vs baseline: 1.2983x; 1.2142x over previous
//
#include <hip/hip_runtime.h>

typedef unsigned short u16;
typedef unsigned int   u32;
typedef __attribute__((ext_vector_type(8))) __bf16 bf16x8;
typedef __attribute__((ext_vector_type(4))) float   f32x4;

#define MROWS 16400     // 16 * 1025
#define NPADROWS 16512  // padded rows in bf16 buffers
#define KD 1024
#define MATEL ((size_t)NPADROWS * KD)   // elems per padded matrix
#define NT 32           // K-tiles of 32

__device__ __forceinline__ u16 f2b(float f) {
  union { float f; u32 u; } x; x.f = f;
  return (u16)((x.u + 0x7FFFu + ((x.u >> 16) & 1u)) >> 16);
}
__device__ __forceinline__ float b2f(u16 h) {
  union { u32 u; float f; } x; x.u = ((u32)h) << 16;
  return x.f;
}

__device__ __forceinline__ void gll16(const u16* g, u16* l) {
  __builtin_amdgcn_global_load_lds(
      (const __attribute__((address_space(1))) void*)g,
      (__attribute__((address_space(3))) void*)l, 16, 0, 0);
}

// ---------------------------------------------------------------------------
// Merged prologue: blocks [0,4096) transpose+convert weights; blocks
// [4096,6144) convert q/k/v fp32 -> padded bf16 (grid-stride).
// ---------------------------------------------------------------------------
__global__ __launch_bounds__(256) void k_pre(
    const float* __restrict__ W0, const float* __restrict__ W1,
    const float* __restrict__ W2, const float* __restrict__ W3,
    u16* __restrict__ T,
    const float* __restrict__ q, const float* __restrict__ k,
    const float* __restrict__ v, u16* __restrict__ dst)
{
  if (blockIdx.x < 4096) {
    __shared__ float tile[32][33];
    int z = blockIdx.x >> 10;
    int tl = blockIdx.x & 1023;
    int k0 = (tl >> 5) * 32, n0 = (tl & 31) * 32;
    int tx = threadIdx.x & 31, ty = threadIdx.x >> 5;
    const float* W = (z == 0) ? W0 : (z == 1) ? W1 : (z == 2) ? W2 : W3;
    u16* Tz = T + (size_t)z * KD * KD;
#pragma unroll
    for (int r = ty; r < 32; r += 8)
      tile[r][tx] = W[(size_t)(k0 + r) * KD + n0 + tx];
    __syncthreads();
#pragma unroll
    for (int r = ty; r < 32; r += 8)
      Tz[(size_t)(n0 + r) * KD + k0 + tx] = f2b(tile[tx][r]);
  } else {
    int cid = blockIdx.x - 4096;
    const size_t CH_PER_MAT = MATEL / 8;
    const size_t total = 3 * CH_PER_MAT;
    for (size_t c = (size_t)cid * 256 + threadIdx.x; c < total;
         c += (size_t)2048 * 256) {
      size_t z = c / CH_PER_MAT;
      size_t r = c - z * CH_PER_MAT;
      size_t row = r >> 7;
      int col8 = (int)(r & 127) * 8;
      u16* o = dst + z * MATEL + row * KD + col8;
      if (row < MROWS) {
        const float* s = ((z == 0) ? q : (z == 1) ? k : v) + row * KD + col8;
        float4 f0 = *(const float4*)s;
        float4 f1 = *(const float4*)(s + 4);
        ushort4 o0; o0.x = f2b(f0.x); o0.y = f2b(f0.y); o0.z = f2b(f0.z); o0.w = f2b(f0.w);
        ushort4 o1; o1.x = f2b(f1.x); o1.y = f2b(f1.y); o1.z = f2b(f1.z); o1.w = f2b(f1.w);
        *(ushort4*)o = o0; *(ushort4*)(o + 4) = o1;
      } else {
        ushort4 zz; zz.x = zz.y = zz.z = zz.w = 0;
        *(ushort4*)o = zz; *(ushort4*)(o + 4) = zz;
      }
    }
  }
}

// ---------------------------------------------------------------------------
// 2-phase prefetch bf16 MFMA GEMM (R12-verified, FROZEN): BK=32 +
// quarter-wave-correct XOR swizzle, 128x128 tile, 4 waves 2x2, 32KB LDS.
// ---------------------------------------------------------------------------
template<bool OUT_FP32>
__global__ __launch_bounds__(256) void k_gemm(
    const u16* __restrict__ Ab, const u16* __restrict__ Bt,
    u16* __restrict__ Cb, float* __restrict__ Cf,
    const float* __restrict__ bias, int nwg)
{
  __shared__ u16 lds[2 * 8192];   // buf: A[128][32] (4096) + B[128][32] (4096)

  int lin = blockIdx.x;
  int cpx = nwg >> 3;                       // nwg % 8 == 0
  int swz = (lin & 7) * cpx + (lin >> 3);   // bijective XCD swizzle
  int bn = swz & 7;
  int rest = swz >> 3;
  int bm = rest % 129;
  int z  = rest / 129;

  int t = threadIdx.x;
  int w = t >> 6, l = t & 63;
  int lrow = l & 15, kgrp = l >> 4;
  int wm = (w >> 1) * 64, wn = (w & 1) * 64;

  int srow = w * 16 + (l >> 2);
  int scol = ((l & 3) ^ ((srow >> 1) & 3)) * 8;
  const u16* gA  = Ab + (size_t)z * MATEL + (size_t)(bm * 128 + srow) * KD + scol;
  const u16* gA2 = gA + (size_t)64 * KD;   // row+64: (r>>1)&3 unchanged
  const u16* gB  = Bt + (size_t)z * (1024 * 1024) + (size_t)(bn * 128 + srow) * KD + scol;
  const u16* gB2 = gB + (size_t)64 * KD;
  int dA0 = w * 512;
  int dA1 = 2048 + w * 512;
  int dB0 = 4096 + w * 512;
  int dB1 = 6144 + w * 512;

  int qr = (lrow >> 1) & 3;
  int aoff[4], boff[4];
#pragma unroll
  for (int fm = 0; fm < 4; ++fm)
    aoff[fm] = (wm + fm * 16 + lrow) * 32 + ((kgrp ^ qr) * 8);
#pragma unroll
  for (int fn = 0; fn < 4; ++fn)
    boff[fn] = 4096 + (wn + fn * 16 + lrow) * 32 + ((kgrp ^ qr) * 8);

  f32x4 acc[4][4] = {};

#define STAGE(B) { u16* L = lds + (B) * 8192;                         \
    gll16(gA,  L + dA0); gll16(gA2, L + dA1);                         \
    gll16(gB,  L + dB0); gll16(gB2, L + dB1);                         \
    gA += 32; gA2 += 32; gB += 32; gB2 += 32; }

  STAGE(0);
  __syncthreads();

  int buf = 0;
#pragma unroll 2
  for (int kt = 0; kt < NT; ++kt) {
    if (kt + 1 < NT) STAGE(buf ^ 1);   // issue next tile FIRST

    const u16* Lb = lds + buf * 8192;
    bf16x8 af[4], bfr[4];
#pragma unroll
    for (int fm = 0; fm < 4; ++fm)
      af[fm] = *(const bf16x8*)(Lb + aoff[fm]);
#pragma unroll
    for (int fn = 0; fn < 4; ++fn)
      bfr[fn] = *(const bf16x8*)(Lb + boff[fn]);
#pragma unroll
    for (int fm = 0; fm < 4; ++fm)
#pragma unroll
      for (int fn = 0; fn < 4; ++fn)
        acc[fm][fn] = __builtin_amdgcn_mfma_f32_16x16x32_bf16(af[fm], bfr[fn], acc[fm][fn], 0, 0, 0);

    __syncthreads();
    buf ^= 1;
  }
#undef STAGE

  // epilogue: C/D layout col=lane&15, row=(lane>>4)*4+reg  [m89-verified]
#pragma unroll
  for (int fm = 0; fm < 4; ++fm) {
#pragma unroll
    for (int fn = 0; fn < 4; ++fn) {
      int gcol = bn * 128 + wn + fn * 16 + lrow;
#pragma unroll
      for (int r = 0; r < 4; ++r) {
        int grow = bm * 128 + wm + fm * 16 + kgrp * 4 + r;
        if constexpr (OUT_FP32) {
          if (grow < MROWS)
            Cf[(size_t)grow * KD + gcol] = acc[fm][fn][r] + bias[gcol];
        } else {
          Cb[(size_t)z * MATEL + (size_t)grow * KD + gcol] = f2b(acc[fm][fn][r]);
        }
      }
    }
  }
}

// ---------------------------------------------------------------------------
// Merged attention v3 (latency-optimized): blocks [0,256) = dense BOS-row
// attention (FIRST, so the long blocks overlap the nearby wave instead of
// tailing); blocks [256,4352) = 2x2 query-tiled nearby attention.
// Nearby changes vs R13: branch-free K/V gathers (clamped row index,
// unconditional loads -> compiler can hoist/pipeline; masked results flow
// through -3e38 -> exp=0 -> p*garbage=0). BOS PV vectorized (ushort4,
// 16-way j-split, 4-wide tree reduce).
// ---------------------------------------------------------------------------
__global__ __launch_bounds__(256) void k_attn(
    const u16* __restrict__ Qp, const u16* __restrict__ Kp,
    const u16* __restrict__ Vp, u16* __restrict__ AO)
{
  int t = threadIdx.x;

  if (blockIdx.x >= 256) {
    // ---------------- nearby attention ----------------
    __shared__ float sdp[4][16][37];   // dots, then probs in place
    __shared__ int   keys[37];
    __shared__ unsigned long long incm[4];

    int bid = blockIdx.x - 256;
    int b = bid >> 8;
    int tile = bid & 255;
    int pi0 = (tile >> 4) * 2, pj0 = (tile & 15) * 2;
    size_t rowbase = (size_t)b * 1025;

    int iq[4];
#pragma unroll
    for (int qi = 0; qi < 4; ++qi)
      iq[qi] = 1 + (pi0 + (qi >> 1)) * 32 + (pj0 + (qi & 1));

    if (t < 37) {
      if (t < 36) {
        int r = pi0 - 2 + t / 6, c = pj0 - 2 + t % 6;
        keys[t] = (r >= 0 && r < 32 && c >= 0 && c < 32) ? (1 + r * 32 + c) : -1;
      } else {
        keys[36] = 0;  // BOS always unmasked
      }
    }
    if (t < 4) {
      int di = t >> 1, dj = t & 1;
      unsigned long long m = 1ull << 36;
      for (int j = 0; j < 36; ++j) {
        int wr = j / 6, wc = j % 6;
        if (wr >= di && wr < di + 5 && wc >= dj && wc < dj + 5) m |= 1ull << j;
      }
      incm[t] = m;
    }

    // direct global->reg q staging: thread owns head hD, k-seg e (16 elems)
    int e = t & 3;
    int hD = (t >> 2) & 15;
    float qreg[4][16];
#pragma unroll
    for (int qi = 0; qi < 4; ++qi) {
      const u16* qp = Qp + (rowbase + iq[qi]) * 1024 + hD * 64 + e * 16;
      uint4 a0 = *(const uint4*)qp;
      uint4 a1 = *(const uint4*)(qp + 8);
      u32 uu[8] = {a0.x, a0.y, a0.z, a0.w, a1.x, a1.y, a1.z, a1.w};
#pragma unroll
      for (int u = 0; u < 8; ++u) {
        qreg[qi][u * 2]     = __uint_as_float(uu[u] << 16);
        qreg[qi][u * 2 + 1] = __uint_as_float(uu[u] & 0xffff0000u);
      }
    }
    __syncthreads();   // keys/incm ready

    // dots: 592 items (j,h) x 4 queries; 4 lanes cooperate per item.
    // Branch-free: clamped row, unconditional loads (hoistable).
#pragma unroll
    for (int p = 0; p < 10; ++p) {
      int idx = p * 64 + (t >> 2);
      int j = idx >> 4; if (j > 36) j = 36;
      int key = keys[j];
      int krow = key < 0 ? 0 : key;
      const u16* kp = Kp + (rowbase + krow) * 1024 + hD * 64 + e * 16;
      uint4 kv0 = *(const uint4*)kp;
      uint4 kv1 = *(const uint4*)(kp + 8);
      float s0 = 0.f, s1 = 0.f, s2 = 0.f, s3 = 0.f;
      u32 uu[8] = {kv0.x, kv0.y, kv0.z, kv0.w, kv1.x, kv1.y, kv1.z, kv1.w};
#pragma unroll
      for (int u = 0; u < 8; ++u) {
        float lo = __uint_as_float(uu[u] << 16);
        float hi = __uint_as_float(uu[u] & 0xffff0000u);
        s0 += qreg[0][u * 2] * lo + qreg[0][u * 2 + 1] * hi;
        s1 += qreg[1][u * 2] * lo + qreg[1][u * 2 + 1] * hi;
        s2 += qreg[2][u * 2] * lo + qreg[2][u * 2 + 1] * hi;
        s3 += qreg[3][u * 2] * lo + qreg[3][u * 2 + 1] * hi;
      }
      s0 += __shfl_xor(s0, 1); s0 += __shfl_xor(s0, 2);
      s1 += __shfl_xor(s1, 1); s1 += __shfl_xor(s1, 2);
      s2 += __shfl_xor(s2, 1); s2 += __shfl_xor(s2, 2);
      s3 += __shfl_xor(s3, 1); s3 += __shfl_xor(s3, 2);
      if (idx < 592) {
        float sv = (e == 0) ? s0 : (e == 1) ? s1 : (e == 2) ? s2 : s3;
        sdp[e][hD][j] = (key >= 0) ? sv * 0.125f : -3.0e38f;
      }
    }
    __syncthreads();

    { // softmax in place: 64 rows (qi,h) x 4 lanes; lane e scans e,e+4,...
      int row = t >> 2;
      int qi = row >> 4, hh = row & 15;
      unsigned long long inc = incm[qi];
      float dv[10];
      float m = -3.0e38f;
#pragma unroll
      for (int s = 0; s < 10; ++s) {
        int j = e + s * 4;
        float d = -3.0e38f;
        if (j < 37) {
          d = sdp[qi][hh][j];
          if (!((inc >> j) & 1)) d = -3.0e38f;
        }
        dv[s] = d;
        m = fmaxf(m, d);
      }
      m = fmaxf(m, __shfl_xor(m, 1));
      m = fmaxf(m, __shfl_xor(m, 2));
      float sum = 0.f;
      float pv[10];
#pragma unroll
      for (int s = 0; s < 10; ++s) {
        int j = e + s * 4;
        float p = (j < 37) ? __expf(dv[s] - m) : 0.f;
        pv[s] = p; sum += p;
      }
      sum += __shfl_xor(sum, 1);
      sum += __shfl_xor(sum, 2);
      float inv = 1.f / sum;
#pragma unroll
      for (int s = 0; s < 10; ++s) {
        int j = e + s * 4;
        if (j < 37) sdp[qi][hh][j] = pv[s] * inv;
      }
    }
    __syncthreads();

    { // PV: branch-free (clamped row; p=0 kills masked contributions)
      int h = t >> 4;
      int c0 = t * 4;
      float a[4][4] = {};
#pragma unroll 4
      for (int j = 0; j < 37; ++j) {
        int key = keys[j];
        int krow = key < 0 ? 0 : key;
        ushort4 vv = *(const ushort4*)(Vp + (rowbase + krow) * 1024 + c0);
        float v0 = b2f(vv.x), v1 = b2f(vv.y), v2 = b2f(vv.z), v3 = b2f(vv.w);
#pragma unroll
        for (int qi = 0; qi < 4; ++qi) {
          float p = sdp[qi][h][j];
          a[qi][0] += p * v0; a[qi][1] += p * v1;
          a[qi][2] += p * v2; a[qi][3] += p * v3;
        }
      }
#pragma unroll
      for (int qi = 0; qi < 4; ++qi) {
        ushort4 o;
        o.x = f2b(a[qi][0]); o.y = f2b(a[qi][1]);
        o.z = f2b(a[qi][2]); o.w = f2b(a[qi][3]);
        *(ushort4*)&AO[(rowbase + iq[qi]) * 1024 + c0] = o;
      }
    }
  } else {
    // ---------------- BOS-row dense attention ----------------
    __shared__ float q0[64];
    __shared__ float pr[1025];
    __shared__ float red[256];
    __shared__ float red4[256][4];
    int bid = blockIdx.x;
    int b = bid >> 4, h = bid & 15;
    size_t rowbase = (size_t)b * 1025;

    if (t < 64) q0[t] = b2f(Qp[rowbase * 1024 + h * 64 + t]);
    __syncthreads();

    float lmax = -3.0e38f;
    for (int j = t; j < 1025; j += 256) {
      const u16* kp = Kp + (rowbase + j) * 1024 + h * 64;
      float s = 0.f;
#pragma unroll
      for (int e = 0; e < 64; e += 4) {
        ushort4 kv = *(const ushort4*)(kp + e);
        s += q0[e + 0] * b2f(kv.x) + q0[e + 1] * b2f(kv.y)
           + q0[e + 2] * b2f(kv.z) + q0[e + 3] * b2f(kv.w);
      }
      s *= 0.125f;
      pr[j] = s;
      lmax = fmaxf(lmax, s);
    }
    red[t] = lmax; __syncthreads();
    for (int s = 128; s > 0; s >>= 1) {
      if (t < s) red[t] = fmaxf(red[t], red[t + s]);
      __syncthreads();
    }
    float m = red[0]; __syncthreads();

    float lsum = 0.f;
    for (int j = t; j < 1025; j += 256) {
      float p = __expf(pr[j] - m);
      pr[j] = p; lsum += p;
    }
    red[t] = lsum; __syncthreads();
    for (int s = 128; s > 0; s >>= 1) {
      if (t < s) red[t] += red[t + s];
      __syncthreads();
    }
    float inv = 1.f / red[0]; __syncthreads();

    // PV vectorized: dim-group g16 = t&15 (4 dims), j-group grp = t>>4
    int g16 = t & 15, grp = t >> 4;
    int c0 = h * 64 + g16 * 4;
    float a0 = 0, a1 = 0, a2 = 0, a3 = 0;
    for (int j = grp; j < 1025; j += 16) {
      float p = pr[j];
      ushort4 vv = *(const ushort4*)(Vp + (rowbase + j) * 1024 + c0);
      a0 += p * b2f(vv.x); a1 += p * b2f(vv.y);
      a2 += p * b2f(vv.z); a3 += p * b2f(vv.w);
    }
    red4[t][0] = a0; red4[t][1] = a1; red4[t][2] = a2; red4[t][3] = a3;
    __syncthreads();
    for (int s = 128; s >= 16; s >>= 1) {
      if (t < s) {
#pragma unroll
        for (int kx = 0; kx < 4; ++kx) red4[t][kx] += red4[t + s][kx];
      }
      __syncthreads();
    }
    if (t < 16) {
      ushort4 o;
      o.x = f2b(red4[t][0] * inv); o.y = f2b(red4[t][1] * inv);
      o.z = f2b(red4[t][2] * inv); o.w = f2b(red4[t][3] * inv);
      *(ushort4*)&AO[rowbase * 1024 + h * 64 + t * 4] = o;
    }
  }
}

// ---------------------------------------------------------------------------
extern "C" void kernel_launch(void* const* d_in, const int* in_sizes, int n_in,
                              void* d_out, int out_size, void* d_ws, size_t ws_size,
                              hipStream_t stream) {
  const float* q  = (const float*)d_in[0];
  const float* k  = (const float*)d_in[1];
  const float* v  = (const float*)d_in[2];
  const float* Wq = (const float*)d_in[3];
  const float* Wk = (const float*)d_in[4];
  const float* Wv = (const float*)d_in[5];
  const float* Wo = (const float*)d_in[6];
  const float* bo = (const float*)d_in[7];
  float* out = (float*)d_out;

  // workspace (u16 units), ~211.3 MB total:
  //   wt:  4M            (Wq^T,Wk^T,Wv^T,Wo^T bf16)
  //   qb:  3*MATEL       (q,k,v converted padded bf16)  [AO aliases qb]
  //   Qp:  3*MATEL       (projected Q,K,V bf16 padded)
  u16* wt = (u16*)d_ws;
  u16* qb = wt + (size_t)4 * 1024 * 1024;
  u16* Qp = qb + 3 * MATEL;
  u16* Kp = Qp + MATEL;
  u16* Vp = Kp + MATEL;
  u16* AO = qb;  // alias: qb dead after projection GEMM

  // merged wtrans (4096 blocks) + convert (2048 virtual blocks)
  k_pre<<<6144, 256, 0, stream>>>(Wq, Wk, Wv, Wo, wt, q, k, v, qb);

  // Q/K/V projections (z = 0,1,2 via grid decode): nwg = 8*129*3 = 3096
  k_gemm<false><<<3096, 256, 0, stream>>>(qb, wt, Qp, nullptr, nullptr, 3096);

  // merged attention: 256 BOS-row blocks FIRST + 4096 nearby blocks
  k_attn<<<4352, 256, 0, stream>>>(Qp, Kp, Vp, AO);

  // output projection: nwg = 8*129 = 1032, fp32 out + bias
  k_gemm<true><<<1032, 256, 0, stream>>>(AO, wt + (size_t)3 * 1024 * 1024,
                                         nullptr, out, bo, 1032);
}

// Round 15
// 350.011 us; speedup vs baseline: 1.3174x; 1.0147x over previous
//
#include <hip/hip_runtime.h>

typedef unsigned short u16;
typedef unsigned int   u32;
typedef __attribute__((ext_vector_type(8))) __bf16 bf16x8;
typedef __attribute__((ext_vector_type(4))) float   f32x4;

#define MROWS 16400     // 16 * 1025
#define NPADROWS 16512  // padded rows in bf16 buffers
#define KD 1024
#define MATEL ((size_t)NPADROWS * KD)   // elems per padded matrix
#define NT 32           // K-tiles of 32

__device__ __forceinline__ u16 f2b(float f) {
  union { float f; u32 u; } x; x.f = f;
  return (u16)((x.u + 0x7FFFu + ((x.u >> 16) & 1u)) >> 16);
}
__device__ __forceinline__ float b2f(u16 h) {
  union { u32 u; float f; } x; x.u = ((u32)h) << 16;
  return x.f;
}

__device__ __forceinline__ void gll16(const u16* g, u16* l) {
  __builtin_amdgcn_global_load_lds(
      (const __attribute__((address_space(1))) void*)g,
      (__attribute__((address_space(3))) void*)l, 16, 0, 0);
}

// ---------------------------------------------------------------------------
// Merged prologue: blocks [0,4096) transpose+convert weights; blocks
// [4096,6144) convert q/k/v fp32 -> padded bf16 (grid-stride).
// ---------------------------------------------------------------------------
__global__ __launch_bounds__(256) void k_pre(
    const float* __restrict__ W0, const float* __restrict__ W1,
    const float* __restrict__ W2, const float* __restrict__ W3,
    u16* __restrict__ T,
    const float* __restrict__ q, const float* __restrict__ k,
    const float* __restrict__ v, u16* __restrict__ dst)
{
  if (blockIdx.x < 4096) {
    __shared__ float tile[32][33];
    int z = blockIdx.x >> 10;
    int tl = blockIdx.x & 1023;
    int k0 = (tl >> 5) * 32, n0 = (tl & 31) * 32;
    int tx = threadIdx.x & 31, ty = threadIdx.x >> 5;
    const float* W = (z == 0) ? W0 : (z == 1) ? W1 : (z == 2) ? W2 : W3;
    u16* Tz = T + (size_t)z * KD * KD;
#pragma unroll
    for (int r = ty; r < 32; r += 8)
      tile[r][tx] = W[(size_t)(k0 + r) * KD + n0 + tx];
    __syncthreads();
#pragma unroll
    for (int r = ty; r < 32; r += 8)
      Tz[(size_t)(n0 + r) * KD + k0 + tx] = f2b(tile[tx][r]);
  } else {
    int cid = blockIdx.x - 4096;
    const size_t CH_PER_MAT = MATEL / 8;
    const size_t total = 3 * CH_PER_MAT;
    for (size_t c = (size_t)cid * 256 + threadIdx.x; c < total;
         c += (size_t)2048 * 256) {
      size_t z = c / CH_PER_MAT;
      size_t r = c - z * CH_PER_MAT;
      size_t row = r >> 7;
      int col8 = (int)(r & 127) * 8;
      u16* o = dst + z * MATEL + row * KD + col8;
      if (row < MROWS) {
        const float* s = ((z == 0) ? q : (z == 1) ? k : v) + row * KD + col8;
        float4 f0 = *(const float4*)s;
        float4 f1 = *(const float4*)(s + 4);
        ushort4 o0; o0.x = f2b(f0.x); o0.y = f2b(f0.y); o0.z = f2b(f0.z); o0.w = f2b(f0.w);
        ushort4 o1; o1.x = f2b(f1.x); o1.y = f2b(f1.y); o1.z = f2b(f1.z); o1.w = f2b(f1.w);
        *(ushort4*)o = o0; *(ushort4*)(o + 4) = o1;
      } else {
        ushort4 zz; zz.x = zz.y = zz.z = zz.w = 0;
        *(ushort4*)o = zz; *(ushort4*)(o + 4) = zz;
      }
    }
  }
}

// ---------------------------------------------------------------------------
// QKV GEMM: 4-phase-per-K-tile + counted vmcnt (the untried cell combining
// R9's race-verified triple-buffer vmcnt(4) ledger with R10's race-verified
// phase body), 256x256 tile, BK=32, 512 thr / 8 waves (2M x 4N, wave tile
// 128x64), 3 LDS bufs x 32KB (96KB -> 1 block/CU), R12's quarter-wave-
// correct chunk swizzle ((r>>1)&3 XOR, measured 0 conflicts).
// Ledger (R9): prologue STAGE(0,1)+vmcnt(4); loop: STAGE(kt+2) at top
// (4 loads/wave), 4 quadrant phases {reads -> BAR -> setprio 8xMFMA -> BAR},
// end vmcnt(4) (tile kt+1 resident, kt+2 in flight) - never drains to 0.
// __launch_bounds__(512,1): no spill (R9-verified; spill corrupts vmcnt).
// ---------------------------------------------------------------------------
template<bool OUT_FP32>
__global__ __launch_bounds__(512, 1) void k_gemm256(
    const u16* __restrict__ Ab, const u16* __restrict__ Bt,
    u16* __restrict__ Cb, float* __restrict__ Cf,
    const float* __restrict__ bias, int nwg)
{
  __shared__ u16 lds[3 * 16384];   // buf: A[256][32] (8192) + B[256][32] (8192)

  // bijective XCD swizzle (m204), bn-fastest for A-panel L2 reuse
  int lin = blockIdx.x;
  int qq = nwg >> 3, r8 = nwg & 7;
  int xcd = lin & 7, pos = lin >> 3;
  int wg = (xcd < r8 ? xcd * (qq + 1) : r8 * (qq + 1) + (xcd - r8) * qq) + pos;
  int bn = wg & 3;
  int rest = wg >> 2;
  int bm = rest % 65;
  int z  = rest / 65;

  int t = threadIdx.x;
  int w = t >> 6, l = t & 63;
  int lrow = l & 15, kgrp = l >> 4;
  int wrow = w >> 2, wcol = w & 3;     // 2M x 4N wave grid

  // ---- staging: A 2 issues (rows pr / 128+pr), B 2 issues. Thread t:
  // row-in-half pr = t>>2, phys chunk t&3; source col chunk = phys ^
  // ((pr>>1)&3)  [= (t>>3)&3]  (quarter-wave-correct, R12-verified form).
  int pr = t >> 2;
  int ccl = ((t & 3) ^ ((t >> 3) & 3)) * 8;
  int ar0 = bm * 256 + pr;        if (ar0 > NPADROWS - 1) ar0 = NPADROWS - 1;
  int ar1 = bm * 256 + 128 + pr;  if (ar1 > NPADROWS - 1) ar1 = NPADROWS - 1;
  const u16* gA0 = Ab + (size_t)z * MATEL + (size_t)ar0 * KD + ccl;
  const u16* gA1 = Ab + (size_t)z * MATEL + (size_t)ar1 * KD + ccl;
  const u16* gB0 = Bt + (size_t)z * (1024 * 1024) + (size_t)(bn * 256 + pr) * KD + ccl;
  const u16* gB1 = gB0 + (size_t)128 * KD;

  // ---- fragment read offsets: logical chunk kgrp at row r -> phys
  // kgrp ^ ((r>>1)&3) = kgrp ^ ((lrow>>1)&3) (frag rows differ by mult of 16)
  int qr = (lrow >> 1) & 3;
  int xk = (kgrp ^ qr) * 8;

  f32x4 acc[8][4] = {};
  bf16x8 afr[4], bfr2[2];

#define STAGE(B) { u16* L = lds + (B) * 16384;                          \
    gll16(gA0, L + w * 512);          gll16(gA1, L + 4096 + w * 512);   \
    gll16(gB0, L + 8192 + w * 512);   gll16(gB1, L + 12288 + w * 512);  \
    gA0 += 32; gA1 += 32; gB0 += 32; gB1 += 32; }

#define WAITV4 do { __builtin_amdgcn_sched_barrier(0);                  \
    asm volatile("s_waitcnt vmcnt(4)" ::: "memory");                    \
    __builtin_amdgcn_sched_barrier(0); } while (0)
#define WAITV0 do { __builtin_amdgcn_sched_barrier(0);                  \
    asm volatile("s_waitcnt vmcnt(0)" ::: "memory");                    \
    __builtin_amdgcn_sched_barrier(0); } while (0)
#define BAR do { __builtin_amdgcn_sched_barrier(0);                     \
    __builtin_amdgcn_s_barrier();                                       \
    __builtin_amdgcn_sched_barrier(0); } while (0)

#define READ_A(FM0) {                                                   \
    _Pragma("unroll")                                                   \
    for (int qa = 0; qa < 4; ++qa)                                      \
      afr[qa] = *(const bf16x8*)(Lb + (wrow * 128 + (FM0 + qa) * 16 + lrow) * 32 + xk); }
#define READ_B(FN0) {                                                   \
    _Pragma("unroll")                                                   \
    for (int qb = 0; qb < 2; ++qb)                                      \
      bfr2[qb] = *(const bf16x8*)(Lb + 8192 + (wcol * 64 + (FN0 + qb) * 16 + lrow) * 32 + xk); }
#define MFMA_Q(FM0, FN0) {                                              \
    __builtin_amdgcn_s_setprio(1);                                      \
    _Pragma("unroll")                                                   \
    for (int qa = 0; qa < 4; ++qa)                                      \
      _Pragma("unroll")                                                 \
      for (int qb = 0; qb < 2; ++qb)                                    \
        acc[FM0 + qa][FN0 + qb] = __builtin_amdgcn_mfma_f32_16x16x32_bf16( \
            afr[qa], bfr2[qb], acc[FM0 + qa][FN0 + qb], 0, 0, 0);       \
    __builtin_amdgcn_s_setprio(0); }

  // prologue: stage tiles 0,1 (8 loads/wave); wait tile 0 (oldest 4) landed
  STAGE(0); STAGE(1);
  WAITV4;
  BAR;

  int cur = 0;
  for (int kt = 0; kt < NT; ++kt) {
    if (kt + 2 < NT) {
      int pre = cur + 2; if (pre >= 3) pre -= 3;
      STAGE(pre);                      // issue tile kt+2 into freed buffer
    }
    const u16* Lb = lds + cur * 16384;
    // phase 1: quadrant (fm0-3, fn0-1)
    READ_A(0); READ_B(0);
    BAR; MFMA_Q(0, 0); BAR;
    // phase 2: quadrant (fm0-3, fn2-3), A reused in regs
    READ_B(2);
    BAR; MFMA_Q(0, 2); BAR;
    // phase 3: quadrant (fm4-7, fn2-3), B reused in regs
    READ_A(4);
    BAR; MFMA_Q(4, 2); BAR;
    // phase 4: quadrant (fm4-7, fn0-1), then counted wait (never drain-0)
    READ_B(0);
    BAR; MFMA_Q(4, 0);
    if (kt + 1 < NT) {
      if (kt + 2 < NT) { WAITV4; }     // tile kt+1 landed, kt+2 in flight
      else            { WAITV0; }      // drain last tile
      BAR;
    }
    cur += 1; if (cur == 3) cur = 0;
  }
#undef STAGE
#undef WAITV4
#undef WAITV0
#undef BAR
#undef READ_A
#undef READ_B
#undef MFMA_Q

  // epilogue: C/D layout col=lane&15, row=(lane>>4)*4+reg  [m89-verified]
#pragma unroll
  for (int fm = 0; fm < 8; ++fm) {
#pragma unroll
    for (int fn = 0; fn < 4; ++fn) {
      int gcol = bn * 256 + wcol * 64 + fn * 16 + lrow;
#pragma unroll
      for (int r = 0; r < 4; ++r) {
        int grow = bm * 256 + wrow * 128 + fm * 16 + kgrp * 4 + r;
        if constexpr (OUT_FP32) {
          if (grow < MROWS)
            Cf[(size_t)grow * KD + gcol] = acc[fm][fn][r] + bias[gcol];
        } else {
          if (grow < NPADROWS)
            Cb[(size_t)z * MATEL + (size_t)grow * KD + gcol] = f2b(acc[fm][fn][r]);
        }
      }
    }
  }
}

// ---------------------------------------------------------------------------
// Out-proj GEMM (R12-verified 128² kernel, FROZEN): BK=32 + quarter-wave
// XOR swizzle, 4 waves 2x2, 32KB LDS, 1 __syncthreads/K-tile.
// ---------------------------------------------------------------------------
template<bool OUT_FP32>
__global__ __launch_bounds__(256) void k_gemm(
    const u16* __restrict__ Ab, const u16* __restrict__ Bt,
    u16* __restrict__ Cb, float* __restrict__ Cf,
    const float* __restrict__ bias, int nwg)
{
  __shared__ u16 lds[2 * 8192];

  int lin = blockIdx.x;
  int cpx = nwg >> 3;
  int swz = (lin & 7) * cpx + (lin >> 3);
  int bn = swz & 7;
  int rest = swz >> 3;
  int bm = rest % 129;
  int z  = rest / 129;

  int t = threadIdx.x;
  int w = t >> 6, l = t & 63;
  int lrow = l & 15, kgrp = l >> 4;
  int wm = (w >> 1) * 64, wn = (w & 1) * 64;

  int srow = w * 16 + (l >> 2);
  int scol = ((l & 3) ^ ((srow >> 1) & 3)) * 8;
  const u16* gA  = Ab + (size_t)z * MATEL + (size_t)(bm * 128 + srow) * KD + scol;
  const u16* gA2 = gA + (size_t)64 * KD;
  const u16* gB  = Bt + (size_t)z * (1024 * 1024) + (size_t)(bn * 128 + srow) * KD + scol;
  const u16* gB2 = gB + (size_t)64 * KD;
  int dA0 = w * 512;
  int dA1 = 2048 + w * 512;
  int dB0 = 4096 + w * 512;
  int dB1 = 6144 + w * 512;

  int qr = (lrow >> 1) & 3;
  int aoff[4], boff[4];
#pragma unroll
  for (int fm = 0; fm < 4; ++fm)
    aoff[fm] = (wm + fm * 16 + lrow) * 32 + ((kgrp ^ qr) * 8);
#pragma unroll
  for (int fn = 0; fn < 4; ++fn)
    boff[fn] = 4096 + (wn + fn * 16 + lrow) * 32 + ((kgrp ^ qr) * 8);

  f32x4 acc[4][4] = {};

#define STAGE(B) { u16* L = lds + (B) * 8192;                         \
    gll16(gA,  L + dA0); gll16(gA2, L + dA1);                         \
    gll16(gB,  L + dB0); gll16(gB2, L + dB1);                         \
    gA += 32; gA2 += 32; gB += 32; gB2 += 32; }

  STAGE(0);
  __syncthreads();

  int buf = 0;
#pragma unroll 2
  for (int kt = 0; kt < NT; ++kt) {
    if (kt + 1 < NT) STAGE(buf ^ 1);

    const u16* Lb = lds + buf * 8192;
    bf16x8 af[4], bfr[4];
#pragma unroll
    for (int fm = 0; fm < 4; ++fm)
      af[fm] = *(const bf16x8*)(Lb + aoff[fm]);
#pragma unroll
    for (int fn = 0; fn < 4; ++fn)
      bfr[fn] = *(const bf16x8*)(Lb + boff[fn]);
#pragma unroll
    for (int fm = 0; fm < 4; ++fm)
#pragma unroll
      for (int fn = 0; fn < 4; ++fn)
        acc[fm][fn] = __builtin_amdgcn_mfma_f32_16x16x32_bf16(af[fm], bfr[fn], acc[fm][fn], 0, 0, 0);

    __syncthreads();
    buf ^= 1;
  }
#undef STAGE

#pragma unroll
  for (int fm = 0; fm < 4; ++fm) {
#pragma unroll
    for (int fn = 0; fn < 4; ++fn) {
      int gcol = bn * 128 + wn + fn * 16 + lrow;
#pragma unroll
      for (int r = 0; r < 4; ++r) {
        int grow = bm * 128 + wm + fm * 16 + kgrp * 4 + r;
        if constexpr (OUT_FP32) {
          if (grow < MROWS)
            Cf[(size_t)grow * KD + gcol] = acc[fm][fn][r] + bias[gcol];
        } else {
          Cb[(size_t)z * MATEL + (size_t)grow * KD + gcol] = f2b(acc[fm][fn][r]);
        }
      }
    }
  }
}

// ---------------------------------------------------------------------------
// Merged attention (R14-verified, FROZEN): blocks [0,256) = dense BOS-row
// attention first; blocks [256,4352) = 2x2 query-tiled nearby attention with
// branch-free gathers.
// ---------------------------------------------------------------------------
__global__ __launch_bounds__(256) void k_attn(
    const u16* __restrict__ Qp, const u16* __restrict__ Kp,
    const u16* __restrict__ Vp, u16* __restrict__ AO)
{
  int t = threadIdx.x;

  if (blockIdx.x >= 256) {
    __shared__ float sdp[4][16][37];
    __shared__ int   keys[37];
    __shared__ unsigned long long incm[4];

    int bid = blockIdx.x - 256;
    int b = bid >> 8;
    int tile = bid & 255;
    int pi0 = (tile >> 4) * 2, pj0 = (tile & 15) * 2;
    size_t rowbase = (size_t)b * 1025;

    int iq[4];
#pragma unroll
    for (int qi = 0; qi < 4; ++qi)
      iq[qi] = 1 + (pi0 + (qi >> 1)) * 32 + (pj0 + (qi & 1));

    if (t < 37) {
      if (t < 36) {
        int r = pi0 - 2 + t / 6, c = pj0 - 2 + t % 6;
        keys[t] = (r >= 0 && r < 32 && c >= 0 && c < 32) ? (1 + r * 32 + c) : -1;
      } else {
        keys[36] = 0;
      }
    }
    if (t < 4) {
      int di = t >> 1, dj = t & 1;
      unsigned long long m = 1ull << 36;
      for (int j = 0; j < 36; ++j) {
        int wr = j / 6, wc = j % 6;
        if (wr >= di && wr < di + 5 && wc >= dj && wc < dj + 5) m |= 1ull << j;
      }
      incm[t] = m;
    }

    int e = t & 3;
    int hD = (t >> 2) & 15;
    float qreg[4][16];
#pragma unroll
    for (int qi = 0; qi < 4; ++qi) {
      const u16* qp = Qp + (rowbase + iq[qi]) * 1024 + hD * 64 + e * 16;
      uint4 a0 = *(const uint4*)qp;
      uint4 a1 = *(const uint4*)(qp + 8);
      u32 uu[8] = {a0.x, a0.y, a0.z, a0.w, a1.x, a1.y, a1.z, a1.w};
#pragma unroll
      for (int u = 0; u < 8; ++u) {
        qreg[qi][u * 2]     = __uint_as_float(uu[u] << 16);
        qreg[qi][u * 2 + 1] = __uint_as_float(uu[u] & 0xffff0000u);
      }
    }
    __syncthreads();

#pragma unroll
    for (int p = 0; p < 10; ++p) {
      int idx = p * 64 + (t >> 2);
      int j = idx >> 4; if (j > 36) j = 36;
      int key = keys[j];
      int krow = key < 0 ? 0 : key;
      const u16* kp = Kp + (rowbase + krow) * 1024 + hD * 64 + e * 16;
      uint4 kv0 = *(const uint4*)kp;
      uint4 kv1 = *(const uint4*)(kp + 8);
      float s0 = 0.f, s1 = 0.f, s2 = 0.f, s3 = 0.f;
      u32 uu[8] = {kv0.x, kv0.y, kv0.z, kv0.w, kv1.x, kv1.y, kv1.z, kv1.w};
#pragma unroll
      for (int u = 0; u < 8; ++u) {
        float lo = __uint_as_float(uu[u] << 16);
        float hi = __uint_as_float(uu[u] & 0xffff0000u);
        s0 += qreg[0][u * 2] * lo + qreg[0][u * 2 + 1] * hi;
        s1 += qreg[1][u * 2] * lo + qreg[1][u * 2 + 1] * hi;
        s2 += qreg[2][u * 2] * lo + qreg[2][u * 2 + 1] * hi;
        s3 += qreg[3][u * 2] * lo + qreg[3][u * 2 + 1] * hi;
      }
      s0 += __shfl_xor(s0, 1); s0 += __shfl_xor(s0, 2);
      s1 += __shfl_xor(s1, 1); s1 += __shfl_xor(s1, 2);
      s2 += __shfl_xor(s2, 1); s2 += __shfl_xor(s2, 2);
      s3 += __shfl_xor(s3, 1); s3 += __shfl_xor(s3, 2);
      if (idx < 592) {
        float sv = (e == 0) ? s0 : (e == 1) ? s1 : (e == 2) ? s2 : s3;
        sdp[e][hD][j] = (key >= 0) ? sv * 0.125f : -3.0e38f;
      }
    }
    __syncthreads();

    {
      int row = t >> 2;
      int qi = row >> 4, hh = row & 15;
      unsigned long long inc = incm[qi];
      float dv[10];
      float m = -3.0e38f;
#pragma unroll
      for (int s = 0; s < 10; ++s) {
        int j = e + s * 4;
        float d = -3.0e38f;
        if (j < 37) {
          d = sdp[qi][hh][j];
          if (!((inc >> j) & 1)) d = -3.0e38f;
        }
        dv[s] = d;
        m = fmaxf(m, d);
      }
      m = fmaxf(m, __shfl_xor(m, 1));
      m = fmaxf(m, __shfl_xor(m, 2));
      float sum = 0.f;
      float pv[10];
#pragma unroll
      for (int s = 0; s < 10; ++s) {
        int j = e + s * 4;
        float p = (j < 37) ? __expf(dv[s] - m) : 0.f;
        pv[s] = p; sum += p;
      }
      sum += __shfl_xor(sum, 1);
      sum += __shfl_xor(sum, 2);
      float inv = 1.f / sum;
#pragma unroll
      for (int s = 0; s < 10; ++s) {
        int j = e + s * 4;
        if (j < 37) sdp[qi][hh][j] = pv[s] * inv;
      }
    }
    __syncthreads();

    {
      int h = t >> 4;
      int c0 = t * 4;
      float a[4][4] = {};
#pragma unroll 4
      for (int j = 0; j < 37; ++j) {
        int key = keys[j];
        int krow = key < 0 ? 0 : key;
        ushort4 vv = *(const ushort4*)(Vp + (rowbase + krow) * 1024 + c0);
        float v0 = b2f(vv.x), v1 = b2f(vv.y), v2 = b2f(vv.z), v3 = b2f(vv.w);
#pragma unroll
        for (int qi = 0; qi < 4; ++qi) {
          float p = sdp[qi][h][j];
          a[qi][0] += p * v0; a[qi][1] += p * v1;
          a[qi][2] += p * v2; a[qi][3] += p * v3;
        }
      }
#pragma unroll
      for (int qi = 0; qi < 4; ++qi) {
        ushort4 o;
        o.x = f2b(a[qi][0]); o.y = f2b(a[qi][1]);
        o.z = f2b(a[qi][2]); o.w = f2b(a[qi][3]);
        *(ushort4*)&AO[(rowbase + iq[qi]) * 1024 + c0] = o;
      }
    }
  } else {
    __shared__ float q0[64];
    __shared__ float pr[1025];
    __shared__ float red[256];
    __shared__ float red4[256][4];
    int bid = blockIdx.x;
    int b = bid >> 4, h = bid & 15;
    size_t rowbase = (size_t)b * 1025;

    if (t < 64) q0[t] = b2f(Qp[rowbase * 1024 + h * 64 + t]);
    __syncthreads();

    float lmax = -3.0e38f;
    for (int j = t; j < 1025; j += 256) {
      const u16* kp = Kp + (rowbase + j) * 1024 + h * 64;
      float s = 0.f;
#pragma unroll
      for (int e = 0; e < 64; e += 4) {
        ushort4 kv = *(const ushort4*)(kp + e);
        s += q0[e + 0] * b2f(kv.x) + q0[e + 1] * b2f(kv.y)
           + q0[e + 2] * b2f(kv.z) + q0[e + 3] * b2f(kv.w);
      }
      s *= 0.125f;
      pr[j] = s;
      lmax = fmaxf(lmax, s);
    }
    red[t] = lmax; __syncthreads();
    for (int s = 128; s > 0; s >>= 1) {
      if (t < s) red[t] = fmaxf(red[t], red[t + s]);
      __syncthreads();
    }
    float m = red[0]; __syncthreads();

    float lsum = 0.f;
    for (int j = t; j < 1025; j += 256) {
      float p = __expf(pr[j] - m);
      pr[j] = p; lsum += p;
    }
    red[t] = lsum; __syncthreads();
    for (int s = 128; s > 0; s >>= 1) {
      if (t < s) red[t] += red[t + s];
      __syncthreads();
    }
    float inv = 1.f / red[0]; __syncthreads();

    int g16 = t & 15, grp = t >> 4;
    int c0 = h * 64 + g16 * 4;
    float a0 = 0, a1 = 0, a2 = 0, a3 = 0;
    for (int j = grp; j < 1025; j += 16) {
      float p = pr[j];
      ushort4 vv = *(const ushort4*)(Vp + (rowbase + j) * 1024 + c0);
      a0 += p * b2f(vv.x); a1 += p * b2f(vv.y);
      a2 += p * b2f(vv.z); a3 += p * b2f(vv.w);
    }
    red4[t][0] = a0; red4[t][1] = a1; red4[t][2] = a2; red4[t][3] = a3;
    __syncthreads();
    for (int s = 128; s >= 16; s >>= 1) {
      if (t < s) {
#pragma unroll
        for (int kx = 0; kx < 4; ++kx) red4[t][kx] += red4[t + s][kx];
      }
      __syncthreads();
    }
    if (t < 16) {
      ushort4 o;
      o.x = f2b(red4[t][0] * inv); o.y = f2b(red4[t][1] * inv);
      o.z = f2b(red4[t][2] * inv); o.w = f2b(red4[t][3] * inv);
      *(ushort4*)&AO[rowbase * 1024 + h * 64 + t * 4] = o;
    }
  }
}

// ---------------------------------------------------------------------------
extern "C" void kernel_launch(void* const* d_in, const int* in_sizes, int n_in,
                              void* d_out, int out_size, void* d_ws, size_t ws_size,
                              hipStream_t stream) {
  const float* q  = (const float*)d_in[0];
  const float* k  = (const float*)d_in[1];
  const float* v  = (const float*)d_in[2];
  const float* Wq = (const float*)d_in[3];
  const float* Wk = (const float*)d_in[4];
  const float* Wv = (const float*)d_in[5];
  const float* Wo = (const float*)d_in[6];
  const float* bo = (const float*)d_in[7];
  float* out = (float*)d_out;

  // workspace (u16 units), ~211.3 MB total:
  //   wt:  4M            (Wq^T,Wk^T,Wv^T,Wo^T bf16)
  //   qb:  3*MATEL       (q,k,v converted padded bf16)  [AO aliases qb]
  //   Qp:  3*MATEL       (projected Q,K,V bf16 padded)
  u16* wt = (u16*)d_ws;
  u16* qb = wt + (size_t)4 * 1024 * 1024;
  u16* Qp = qb + 3 * MATEL;
  u16* Kp = Qp + MATEL;
  u16* Vp = Kp + MATEL;
  u16* AO = qb;  // alias: qb dead after projection GEMM

  // merged wtrans (4096 blocks) + convert (2048 virtual blocks)
  k_pre<<<6144, 256, 0, stream>>>(Wq, Wk, Wv, Wo, wt, q, k, v, qb);

  // Q/K/V projections: 65 M-tiles x 4 N-tiles x 3 z = 780 blocks
  k_gemm256<false><<<780, 512, 0, stream>>>(qb, wt, Qp, nullptr, nullptr, 780);

  // merged attention: 256 BOS-row blocks FIRST + 4096 nearby blocks
  k_attn<<<4352, 256, 0, stream>>>(Qp, Kp, Vp, AO);

  // output projection (R12 128² kernel): nwg = 8*129 = 1032
  k_gemm<true><<<1032, 256, 0, stream>>>(AO, wt + (size_t)3 * 1024 * 1024,
                                         nullptr, out, bo, 1032);
}